// Round 4
// baseline (412.202 us; speedup 1.0000x reference)
//
#include <hip/hip_runtime.h>
#include <hip/hip_bf16.h>
#include <cstdint>
#include <cstddef>

typedef __bf16 bf16x8 __attribute__((ext_vector_type(8)));
typedef float floatx4 __attribute__((ext_vector_type(4)));

#define NROIS 1000
#define PD    12544   // 256*49
#define K2_1  25088   // 2*PD  (hi/lo interleaved)
#define FC_N  1024
#define K2_2  2048    // 2*1024
#define NLOC  324
#define NSC   81
#define NH    405

// ---- workspace layout v2 (float offsets), total 38,797,312 floats ---------
// Stage A (transpose/roi_pool):  fT [0, 22,282,240)   pooled [25,952,256, end)
// Stage B (fc1 gemm):            W1T [0, 12,845,056)  part [12,845,056, 25,427,968)  (12 slices)
//                                pooled (A) read; all dead after.
// Stage C (fc2/heads):           part2 [0, 16,777,216)  (<=16 slices)
//   fc1  [25,952,256, 27,000,832)   W2T [27,000,832, 28,049,408)
//   WhT  [28,049,408, 28,573,696)   fc2 [28,573,696, 29,622,272)
#define OFF_T2   0u
#define OFF_T3   16777216u
#define OFF_T4   20971520u
#define OFF_T5   22020096u
#define OFF_POOL 25952256u   // pooled_hl: 1024*12544 ushort2 = 12,845,056 "floats"
#define OFF_W1T  0u          // aliases dead fT
#define OFF_PART 12845056u   // fc1 partial: 12 x 1,048,576 = 12,582,912
#define OFF_FC1  25952256u   // overwrites dead pooled
#define OFF_W2T  27000832u
#define OFF_WHT  28049408u
#define OFF_FC2  28573696u
#define OFF_PART2 0u         // fc2/heads partials (W1T dead)

// ---- bf16 hi/lo helpers ----------------------------------------------------
__device__ __forceinline__ unsigned short f2bf(float x) {
    unsigned int u = __float_as_uint(x);
    u = u + 0x7fffu + ((u >> 16) & 1u);          // RNE
    return (unsigned short)(u >> 16);
}
__device__ __forceinline__ float bf2f(unsigned short h) {
    return __uint_as_float(((unsigned int)h) << 16);
}
__device__ __forceinline__ ushort2 split_hl(float f) {
    const unsigned short hi = f2bf(f);
    const unsigned short lo = f2bf(f - bf2f(hi));
    return make_ushort2(hi, lo);
}

// ---------------------------------------------------------------------------
// Fused transpose of all 4 pyramid levels [256][P] -> [P][256] fp32.
// ---------------------------------------------------------------------------
__global__ __launch_bounds__(256) void transpose_feat_kernel(
    const float* __restrict__ f2, const float* __restrict__ f3,
    const float* __restrict__ f4, const float* __restrict__ f5,
    float* __restrict__ fT)
{
    __shared__ float tile[64][65];
    int bx = blockIdx.x;
    const float* src; float* dst; int P;
    if (bx < 1024)      {            src = f2; dst = fT + OFF_T2; P = 65536; }
    else if (bx < 1280) { bx -= 1024; src = f3; dst = fT + OFF_T3; P = 16384; }
    else if (bx < 1344) { bx -= 1280; src = f4; dst = fT + OFF_T4; P = 4096; }
    else                { bx -= 1344; src = f5; dst = fT + OFF_T5; P = 1024; }

    const int p0  = bx * 64;
    const int c0  = blockIdx.y * 64;
    const int col = threadIdx.x & 63;
    const int r0  = threadIdx.x >> 6;
#pragma unroll
    for (int r = r0; r < 64; r += 4)
        tile[r][col] = src[(size_t)(c0 + r) * P + p0 + col];
    __syncthreads();
#pragma unroll
    for (int r = r0; r < 64; r += 4)
        dst[(size_t)(p0 + r) * 256 + c0 + col] = tile[col][r];
}

// ---------------------------------------------------------------------------
// ROI align + 2x2 max.
// Block = (roi, ph), 256 threads:
//   lane (0..63)  = float4 channel group (channels 4*lane .. 4*lane+3)
//   wave (0..3)   = (syy = wave>>1, sx parity = wave&1)
// ---------------------------------------------------------------------------
__global__ __launch_bounds__(256) void roi_pool_kernel(
    const float* __restrict__ fT, const float* __restrict__ rois,
    const int* __restrict__ img_size, ushort2* __restrict__ pooledHL)
{
    const int roi  = blockIdx.x;        // 0..999
    const int ph   = blockIdx.y;        // 0..6
    const int tid  = threadIdx.x;
    const int lane = tid & 63;
    const int wave = tid >> 6;
    const int syy  = wave >> 1;
    const int sxp  = wave & 1;

    const float y1 = rois[roi * 4 + 0];
    const float x1 = rois[roi * 4 + 1];
    const float y2 = rois[roi * 4 + 2];
    const float x2 = rois[roi * 4 + 3];

    const float hh = y2 - y1 + 1.0f;
    const float ww = x2 - x1 + 1.0f;
    float lvlf = floorf(logf(sqrtf(hh * ww) / 224.0f) / 0.693147f + 4.0f);
    lvlf = fminf(fmaxf(lvlf, 2.0f), 5.0f);
    const int lvl = (int)lvlf;

    const float* f;
    int H;
    if (lvl == 2)      { f = fT + OFF_T2; H = 256; }
    else if (lvl == 3) { f = fT + OFF_T3; H = 128; }
    else if (lvl == 4) { f = fT + OFF_T4; H = 64;  }
    else               { f = fT + OFF_T5; H = 32;  }
    const int W = H;

    const float imh = (float)img_size[0] - 1.0f;
    const float imw = (float)img_size[1] - 1.0f;
    const float r0 = y1 * (float)(H - 1) / imh;
    const float r1 = x1 * (float)(W - 1) / imw;
    const float r2 = y2 * (float)(H - 1) / imh;
    const float r3 = x2 * (float)(W - 1) / imw;
    const float hs  = (r2 - r0) * (1.0f / 14.0f);
    const float wst = (r3 - r1) * (1.0f / 14.0f);

    // row pair for this wave's syy (constant across pw)
    const float cy = ((float)(ph * 2 + syy) + 0.5f) * hs + r0;
    const float fy = floorf(cy);
    int   iu  = (int)fy;
    int   idn = (int)ceilf(cy);
    const float ly = cy - fy;
    iu  = min(max(iu, 0),  H - 1);
    idn = min(max(idn, 0), H - 1);
    const float wU = 1.0f - ly, wD = ly;
    const float4* rowU = (const float4*)(f + (size_t)(iu  * W) * 256);
    const float4* rowD = (const float4*)(f + (size_t)(idn * W) * 256);

    __shared__ float4 red[4][7][64];    // 28 KB

#pragma unroll
    for (int pw = 0; pw < 7; ++pw) {
        const int sx = pw * 2 + sxp;
        const float cx = ((float)sx + 0.5f) * wst + r1;
        const float fx = floorf(cx);
        int   il = (int)fx;
        int   ir = (int)ceilf(cx);
        const float lx = cx - fx;
        il = min(max(il, 0), W - 1);
        ir = min(max(ir, 0), W - 1);

        const float4 v00 = rowU[il * 64 + lane];
        const float4 v01 = rowU[ir * 64 + lane];
        const float4 v10 = rowD[il * 64 + lane];
        const float4 v11 = rowD[ir * 64 + lane];
        const float lxm = 1.0f - lx;
        float4 v;
        v.x = (v00.x * lxm + v01.x * lx) * wU + (v10.x * lxm + v11.x * lx) * wD;
        v.y = (v00.y * lxm + v01.y * lx) * wU + (v10.y * lxm + v11.y * lx) * wD;
        v.z = (v00.z * lxm + v01.z * lx) * wU + (v10.z * lxm + v11.z * lx) * wD;
        v.w = (v00.w * lxm + v01.w * lx) * wU + (v10.w * lxm + v11.w * lx) * wD;
        red[wave][pw][lane] = v;
    }
    __syncthreads();

    // 4-way max combine + hi/lo split store: 7*64 = 448 float4 outputs
    for (int idx = tid; idx < 448; idx += 256) {
        const int pw = idx >> 6, cg = idx & 63;
        const float4 a = red[0][pw][cg];
        const float4 b = red[1][pw][cg];
        const float4 c = red[2][pw][cg];
        const float4 d = red[3][pw][cg];
        float4 mv;
        mv.x = fmaxf(fmaxf(a.x, b.x), fmaxf(c.x, d.x));
        mv.y = fmaxf(fmaxf(a.y, b.y), fmaxf(c.y, d.y));
        mv.z = fmaxf(fmaxf(a.z, b.z), fmaxf(c.z, d.z));
        mv.w = fmaxf(fmaxf(a.w, b.w), fmaxf(c.w, d.w));
        union { ushort2 u2[4]; uint4 v4; } pk;
        pk.u2[0] = split_hl(mv.x);
        pk.u2[1] = split_hl(mv.y);
        pk.u2[2] = split_hl(mv.z);
        pk.u2[3] = split_hl(mv.w);
        ushort2* outp = pooledHL + (size_t)roi * PD + (ph * 7 + pw) * 256 + cg * 4;
        *reinterpret_cast<uint4*>(outp) = pk.v4;
    }
}

// ---------------------------------------------------------------------------
// W1 [12544][1024] fp32 -> W1T [1024 rows][25088] bf16 (transposed, hi/lo
// interleaved, GEMM1 k-permutation folded).
// ---------------------------------------------------------------------------
__global__ __launch_bounds__(256) void convert_w1_kernel(
    const float* __restrict__ W1, ushort2* __restrict__ W1T)
{
    __shared__ float tile[64][65];
    const int p0  = blockIdx.x * 64;
    const int n0  = blockIdx.y * 64;
    const int col = threadIdx.x & 63;
    const int r0  = threadIdx.x >> 6;
#pragma unroll
    for (int r = r0; r < 64; r += 4) {
        const int pp   = p0 + r;
        const int ksrc = (pp & 255) * 49 + (pp >> 8);
        tile[r][col] = W1[(size_t)ksrc * 1024 + n0 + col];
    }
    __syncthreads();
#pragma unroll
    for (int nr = r0; nr < 64; nr += 4)
        W1T[(size_t)(n0 + nr) * PD + p0 + col] = split_hl(tile[col][nr]);
}

// ---------------------------------------------------------------------------
// Merged: W2 -> W2T [1024][2048] (grid.y<16) and [Wloc|Wsc] -> WhT [512][2048]
// ---------------------------------------------------------------------------
__global__ __launch_bounds__(256) void convert_w2h_kernel(
    const float* __restrict__ W2, const float* __restrict__ Wloc,
    const float* __restrict__ Wsc, ushort2* __restrict__ W2T,
    ushort2* __restrict__ WhT)
{
    __shared__ float tile[64][65];
    const int p0  = blockIdx.x * 64;
    const int col = threadIdx.x & 63;
    const int r0  = threadIdx.x >> 6;

    if (blockIdx.y < 16) {
        const int n0 = blockIdx.y * 64;
#pragma unroll
        for (int r = r0; r < 64; r += 4)
            tile[r][col] = W2[(size_t)(p0 + r) * 1024 + n0 + col];
        __syncthreads();
#pragma unroll
        for (int nr = r0; nr < 64; nr += 4)
            W2T[(size_t)(n0 + nr) * 1024 + p0 + col] = split_hl(tile[col][nr]);
    } else {
        const int n0 = (blockIdx.y - 16) * 64;
#pragma unroll
        for (int r = r0; r < 64; r += 4) {
            const int pp = p0 + r;
            const int n  = n0 + col;
            float v = 0.0f;
            if (n < NLOC)    v = Wloc[(size_t)pp * NLOC + n];
            else if (n < NH) v = Wsc[(size_t)pp * NSC + (n - NLOC)];
            tile[r][col] = v;
        }
        __syncthreads();
#pragma unroll
        for (int nr = r0; nr < 64; nr += 4)
            WhT[(size_t)(n0 + nr) * 1024 + p0 + col] = split_hl(tile[col][nr]);
    }
}

// ---------------------------------------------------------------------------
// bf16 MFMA GEMM: tile 128(M)x128(N), BK=64, 4 waves (2x2), each wave owns a
// 64x64 sub-tile (acc[4][4] of 16x16 frags). global_load_lds width 16 with
// XOR-swizzled LDS (linear dest + pre-swizzled global source, read-side XOR).
// grid = (splitK, N/128, M/128). 32 KB LDS.
// K-steps distributed over gridDim.x via q/r partition (no divisibility req).
// splitK sized for occupancy AND for the partial-buffer budget (see layout).
// partial[z][m][n], z-stride = (gridDim.z*128)*N.
// ---------------------------------------------------------------------------
__global__ __launch_bounds__(256) void gemm_bf16_kernel(
    const unsigned short* __restrict__ A,
    const unsigned short* __restrict__ B,
    float* __restrict__ partial,
    int K2, int N)
{
    __shared__ __align__(16) unsigned short As[128 * 64];   // 16 KB
    __shared__ __align__(16) unsigned short Bs[128 * 64];   // 16 KB

    const int tid  = threadIdx.x;
    const int lane = tid & 63;
    const int wave = tid >> 6;

    const int totalSteps = K2 >> 6;                 // K2/64
    const int nz = gridDim.x;
    const int z  = blockIdx.x;
    const int q  = totalSteps / nz, r = totalSteps % nz;
    const int myStart = z * q + min(z, r);
    const int mySteps = q + (z < r ? 1 : 0);

    const int n0 = blockIdx.y * 128;
    const int m0 = blockIdx.z * 128;

    const int wr = wave >> 1;            // wave row (0..1) -> M offset wr*64
    const int wc = wave & 1;             // wave col (0..1) -> N offset wc*64

    const int rIn  = lane >> 3;          // 0..7 (row within 8-row stripe)
    const int cSrc = (lane & 7) ^ rIn;   // XOR-swizzled source chunk

    const int mrow = lane & 15, quad = lane >> 4;

    floatx4 acc[4][4];
#pragma unroll
    for (int mi = 0; mi < 4; ++mi)
#pragma unroll
        for (int nj = 0; nj < 4; ++nj)
            acc[mi][nj] = (floatx4){0.f, 0.f, 0.f, 0.f};

    for (int s = 0; s < mySteps; ++s) {
        const int k0 = (myStart + s) * 64;
        // stage A: wave w -> rows [w*32, w*32+32)
#pragma unroll
        for (int qq = 0; qq < 4; ++qq) {
            const int rowBase = wave * 32 + qq * 8;
            const unsigned short* ga =
                A + (size_t)(m0 + rowBase + rIn) * K2 + k0 + cSrc * 8;
            __builtin_amdgcn_global_load_lds(
                (const __attribute__((address_space(1))) void*)ga,
                (__attribute__((address_space(3))) void*)&As[rowBase * 64], 16, 0, 0);
        }
        // stage B: wave w -> rows [w*32, w*32+32)
#pragma unroll
        for (int qq = 0; qq < 4; ++qq) {
            const int rowBase = wave * 32 + qq * 8;
            const unsigned short* gb =
                B + (size_t)(n0 + rowBase + rIn) * K2 + k0 + cSrc * 8;
            __builtin_amdgcn_global_load_lds(
                (const __attribute__((address_space(1))) void*)gb,
                (__attribute__((address_space(3))) void*)&Bs[rowBase * 64], 16, 0, 0);
        }
        __syncthreads();

#pragma unroll
        for (int ks = 0; ks < 2; ++ks) {
            const int chunk = ks * 4 + quad;
            bf16x8 aF[4], bF[4];
#pragma unroll
            for (int mi = 0; mi < 4; ++mi) {
                const int ra = wr * 64 + mi * 16 + mrow;
                aF[mi] = *reinterpret_cast<const bf16x8*>(
                    &As[ra * 64 + ((chunk ^ (ra & 7)) * 8)]);
            }
#pragma unroll
            for (int nj = 0; nj < 4; ++nj) {
                const int rb = wc * 64 + nj * 16 + mrow;
                bF[nj] = *reinterpret_cast<const bf16x8*>(
                    &Bs[rb * 64 + ((chunk ^ (rb & 7)) * 8)]);
            }
#pragma unroll
            for (int mi = 0; mi < 4; ++mi)
#pragma unroll
                for (int nj = 0; nj < 4; ++nj)
                    acc[mi][nj] = __builtin_amdgcn_mfma_f32_16x16x32_bf16(
                        aF[mi], bF[nj], acc[mi][nj], 0, 0, 0);
        }
        __syncthreads();
    }

    // C/D layout: col = lane&15, row = quad*4 + reg
    float* p = partial + (size_t)blockIdx.x * (size_t)(gridDim.z * 128) * N;
#pragma unroll
    for (int mi = 0; mi < 4; ++mi) {
        const int row = m0 + wr * 64 + mi * 16 + quad * 4;
#pragma unroll
        for (int nj = 0; nj < 4; ++nj) {
            const int col = n0 + wc * 64 + nj * 16 + mrow;
#pragma unroll
            for (int rr = 0; rr < 4; ++rr)
                p[(size_t)(row + rr) * N + col] = acc[mi][nj][rr];
        }
    }
}

// ---------------------------------------------------------------------------
// fc = relu(sum_z partial + bias) -> hi/lo bf16 interleaved. float4 path.
// ---------------------------------------------------------------------------
__global__ __launch_bounds__(256) void reduce_fc_kernel(
    const float* __restrict__ partial, const float* __restrict__ bias,
    ushort2* __restrict__ outHL, int nz)
{
    const int i4 = blockIdx.x * 256 + threadIdx.x;
    const int off = i4 * 4;
    const int m = off >> 10, n = off & 1023;
    float4 acc = *reinterpret_cast<const float4*>(partial + off);
    for (int z = 1; z < nz; ++z) {
        const float4 v = *reinterpret_cast<const float4*>(
            partial + (size_t)z * 1024 * 1024 + off);
        acc.x += v.x; acc.y += v.y; acc.z += v.z; acc.w += v.w;
    }
    const float4 bv = *reinterpret_cast<const float4*>(bias + n);
    ushort2* o = outHL + (size_t)m * 1024 + n;
    o[0] = split_hl(fmaxf(acc.x + bv.x, 0.f));
    o[1] = split_hl(fmaxf(acc.y + bv.y, 0.f));
    o[2] = split_hl(fmaxf(acc.z + bv.z, 0.f));
    o[3] = split_hl(fmaxf(acc.w + bv.w, 0.f));
}

// heads: sum partials [z][1024][512], add bias, split-store to out0/out1
__global__ __launch_bounds__(256) void reduce_heads_kernel(
    const float* __restrict__ partial, const float* __restrict__ bloc,
    const float* __restrict__ bsc, float* __restrict__ out0,
    float* __restrict__ out1, int nz)
{
    const int m = blockIdx.x;   // 0..999
    for (int n = threadIdx.x; n < NH; n += 256) {
        float s = 0.f;
        for (int z = 0; z < nz; ++z)
            s += partial[(size_t)z * 1024 * 512 + (size_t)m * 512 + n];
        if (n < NLOC) out0[(size_t)m * NLOC + n] = s + bloc[n];
        else          out1[(size_t)m * NSC + (n - NLOC)] = s + bsc[n - NLOC];
    }
}

// ---------------------------------------------------------------------------
extern "C" void kernel_launch(void* const* d_in, const int* in_sizes, int n_in,
                              void* d_out, int out_size, void* d_ws, size_t ws_size,
                              hipStream_t stream)
{
    const float* f2   = (const float*)d_in[0];
    const float* f3   = (const float*)d_in[1];
    const float* f4   = (const float*)d_in[2];
    const float* f5   = (const float*)d_in[3];
    const float* rois = (const float*)d_in[4];
    const int*   img  = (const int*)d_in[5];
    const float* W1   = (const float*)d_in[6];
    const float* b1   = (const float*)d_in[7];
    const float* W2   = (const float*)d_in[8];
    const float* b2   = (const float*)d_in[9];
    const float* Wloc = (const float*)d_in[10];
    const float* bloc = (const float*)d_in[11];
    const float* Wsc  = (const float*)d_in[12];
    const float* bsc  = (const float*)d_in[13];
    float* out = (float*)d_out;

    float* ws = (float*)d_ws;
    float*   fT     = ws;                            // [0, 22,282,240)
    ushort2* pooled = (ushort2*)(ws + OFF_POOL);
    ushort2* w1t    = (ushort2*)(ws + OFF_W1T);      // dead fT
    float*   part   = ws + OFF_PART;                 // fc1 partial (12 slices)
    float*   part2  = ws + OFF_PART2;                // fc2/heads partial
    ushort2* w2t    = (ushort2*)(ws + OFF_W2T);      // dead pooled region
    ushort2* wht    = (ushort2*)(ws + OFF_WHT);
    ushort2* fc1    = (ushort2*)(ws + OFF_FC1);
    ushort2* fc2    = (ushort2*)(ws + OFF_FC2);

    // 1) feature transpose to [pix][256], all levels fused
    transpose_feat_kernel<<<dim3(1360, 4), 256, 0, stream>>>(f2, f3, f4, f5, fT);

    // 2) ROI pool, block per (roi, ph)  (pooled now at top of workspace)
    roi_pool_kernel<<<dim3(NROIS, 7), 256, 0, stream>>>(fT, rois, img, pooled);

    // 3) W1 conversion (W1T over dead fT)
    convert_w1_kernel<<<dim3(196, 16), 256, 0, stream>>>(W1, w1t);

    // 4) fc1 = relu(pooled @ W1 + b1): grid (k=12, n=8, m=8) = 768 blocks (3/CU)
    gemm_bf16_kernel<<<dim3(12, 8, 8), 256, 0, stream>>>(
        (const unsigned short*)pooled, (const unsigned short*)w1t, part,
        K2_1, 1024);

    // 5) W2/heads conversion AFTER gemm1 (outputs live in dead-pooled region)
    convert_w2h_kernel<<<dim3(16, 23), 256, 0, stream>>>(W2, Wloc, Wsc, w2t, wht);

    reduce_fc_kernel<<<1024, 256, 0, stream>>>(part, b1, fc1, 12);

    // 6) fc2 = relu(fc1 @ W2 + b2): grid (k=16, n=8, m=8) = 1024 blocks (4/CU)
    gemm_bf16_kernel<<<dim3(16, 8, 8), 256, 0, stream>>>(
        (const unsigned short*)fc1, (const unsigned short*)w2t, part2,
        K2_2, 1024);
    reduce_fc_kernel<<<1024, 256, 0, stream>>>(part2, b2, fc2, 16);

    // 7) heads: N=512, grid (k=16, n=4, m=8) = 512 blocks
    gemm_bf16_kernel<<<dim3(16, 4, 8), 256, 0, stream>>>(
        (const unsigned short*)fc2, (const unsigned short*)wht, part2,
        K2_2, 512);
    reduce_heads_kernel<<<NROIS, 256, 0, stream>>>(
        part2, bloc, bsc, out, out + (size_t)NROIS * NLOC, 16);
}

// Round 5
// 343.143 us; speedup vs baseline: 1.2013x; 1.2013x over previous
//
#include <hip/hip_runtime.h>
#include <hip/hip_bf16.h>
#include <cstdint>
#include <cstddef>

typedef __bf16 bf16x8 __attribute__((ext_vector_type(8)));
typedef _Float16 f16x8 __attribute__((ext_vector_type(8)));
typedef float floatx4 __attribute__((ext_vector_type(4)));

#define NROIS 1000
#define PD    12544   // 256*49 = fc1 K (fp16, single)
#define K2_2  2048    // 2*1024 (hi/lo interleaved) for fc2/heads
#define NLOC  324
#define NSC   81
#define NH    405

// ---- workspace layout v3 (float offsets), total <= 38,797,312 floats ------
// Stage A: fT [0, 22,282,240) fp32; pooled fp16 [22,282,240, 28,704,768)
// Stage B (fc1): W1T fp16 [0, 6,422,528) over dead fT;
//                part1 [6,422,528, 14,811,136) = 8 x 1,048,576 fp32
// Stage C: fc1hl [28,704,768, 29,753,344) ushort2 ; W2T [29,753,344, 30,801,920)
//          WhT [30,801,920, 31,326,208) ; fc2hl [31,326,208, 32,374,784)
//          part2 [0, 4,194,304) over dead W1T
#define OFF_T2    0u
#define OFF_T3    16777216u
#define OFF_T4    20971520u
#define OFF_T5    22020096u
#define OFF_POOL  22282240u
#define OFF_W1T   0u
#define OFF_PART1 6422528u
#define OFF_FC1   28704768u
#define OFF_W2T   29753344u
#define OFF_WHT   30801920u
#define OFF_FC2   31326208u
#define OFF_PART2 0u

// ---- bf16 hi/lo helpers ----------------------------------------------------
__device__ __forceinline__ unsigned short f2bf(float x) {
    unsigned int u = __float_as_uint(x);
    u = u + 0x7fffu + ((u >> 16) & 1u);          // RNE
    return (unsigned short)(u >> 16);
}
__device__ __forceinline__ float bf2f(unsigned short h) {
    return __uint_as_float(((unsigned int)h) << 16);
}
__device__ __forceinline__ ushort2 split_hl(float f) {
    const unsigned short hi = f2bf(f);
    const unsigned short lo = f2bf(f - bf2f(hi));
    return make_ushort2(hi, lo);
}

// ---------------------------------------------------------------------------
// Fused transpose of all 4 pyramid levels [256][P] -> [P][256] fp32.
// ---------------------------------------------------------------------------
__global__ __launch_bounds__(256) void transpose_feat_kernel(
    const float* __restrict__ f2, const float* __restrict__ f3,
    const float* __restrict__ f4, const float* __restrict__ f5,
    float* __restrict__ fT)
{
    __shared__ float tile[64][65];
    int bx = blockIdx.x;
    const float* src; float* dst; int P;
    if (bx < 1024)      {            src = f2; dst = fT + OFF_T2; P = 65536; }
    else if (bx < 1280) { bx -= 1024; src = f3; dst = fT + OFF_T3; P = 16384; }
    else if (bx < 1344) { bx -= 1280; src = f4; dst = fT + OFF_T4; P = 4096; }
    else                { bx -= 1344; src = f5; dst = fT + OFF_T5; P = 1024; }

    const int p0  = bx * 64;
    const int c0  = blockIdx.y * 64;
    const int col = threadIdx.x & 63;
    const int r0  = threadIdx.x >> 6;
#pragma unroll
    for (int r = r0; r < 64; r += 4)
        tile[r][col] = src[(size_t)(c0 + r) * P + p0 + col];
    __syncthreads();
#pragma unroll
    for (int r = r0; r < 64; r += 4)
        dst[(size_t)(p0 + r) * 256 + c0 + col] = tile[col][r];
}

// ---------------------------------------------------------------------------
// ROI align + 2x2 max. Output: fp16 [roi][cell*256+c].
// Block = (roi, ph), lane = float4 channel group, wave = (syy, sx parity).
// ---------------------------------------------------------------------------
__global__ __launch_bounds__(256) void roi_pool_kernel(
    const float* __restrict__ fT, const float* __restrict__ rois,
    const int* __restrict__ img_size, _Float16* __restrict__ pooledH)
{
    const int roi  = blockIdx.x;        // 0..999
    const int ph   = blockIdx.y;        // 0..6
    const int tid  = threadIdx.x;
    const int lane = tid & 63;
    const int wave = tid >> 6;
    const int syy  = wave >> 1;
    const int sxp  = wave & 1;

    const float y1 = rois[roi * 4 + 0];
    const float x1 = rois[roi * 4 + 1];
    const float y2 = rois[roi * 4 + 2];
    const float x2 = rois[roi * 4 + 3];

    const float hh = y2 - y1 + 1.0f;
    const float ww = x2 - x1 + 1.0f;
    float lvlf = floorf(logf(sqrtf(hh * ww) / 224.0f) / 0.693147f + 4.0f);
    lvlf = fminf(fmaxf(lvlf, 2.0f), 5.0f);
    const int lvl = (int)lvlf;

    const float* f;
    int H;
    if (lvl == 2)      { f = fT + OFF_T2; H = 256; }
    else if (lvl == 3) { f = fT + OFF_T3; H = 128; }
    else if (lvl == 4) { f = fT + OFF_T4; H = 64;  }
    else               { f = fT + OFF_T5; H = 32;  }
    const int W = H;

    const float imh = (float)img_size[0] - 1.0f;
    const float imw = (float)img_size[1] - 1.0f;
    const float r0 = y1 * (float)(H - 1) / imh;
    const float r1 = x1 * (float)(W - 1) / imw;
    const float r2 = y2 * (float)(H - 1) / imh;
    const float r3 = x2 * (float)(W - 1) / imw;
    const float hs  = (r2 - r0) * (1.0f / 14.0f);
    const float wst = (r3 - r1) * (1.0f / 14.0f);

    const float cy = ((float)(ph * 2 + syy) + 0.5f) * hs + r0;
    const float fy = floorf(cy);
    int   iu  = (int)fy;
    int   idn = (int)ceilf(cy);
    const float ly = cy - fy;
    iu  = min(max(iu, 0),  H - 1);
    idn = min(max(idn, 0), H - 1);
    const float wU = 1.0f - ly, wD = ly;
    const float4* rowU = (const float4*)(f + (size_t)(iu  * W) * 256);
    const float4* rowD = (const float4*)(f + (size_t)(idn * W) * 256);

    __shared__ float4 red[4][7][64];    // 28 KB

#pragma unroll
    for (int pw = 0; pw < 7; ++pw) {
        const int sx = pw * 2 + sxp;
        const float cx = ((float)sx + 0.5f) * wst + r1;
        const float fx = floorf(cx);
        int   il = (int)fx;
        int   ir = (int)ceilf(cx);
        const float lx = cx - fx;
        il = min(max(il, 0), W - 1);
        ir = min(max(ir, 0), W - 1);

        const float4 v00 = rowU[il * 64 + lane];
        const float4 v01 = rowU[ir * 64 + lane];
        const float4 v10 = rowD[il * 64 + lane];
        const float4 v11 = rowD[ir * 64 + lane];
        const float lxm = 1.0f - lx;
        float4 v;
        v.x = (v00.x * lxm + v01.x * lx) * wU + (v10.x * lxm + v11.x * lx) * wD;
        v.y = (v00.y * lxm + v01.y * lx) * wU + (v10.y * lxm + v11.y * lx) * wD;
        v.z = (v00.z * lxm + v01.z * lx) * wU + (v10.z * lxm + v11.z * lx) * wD;
        v.w = (v00.w * lxm + v01.w * lx) * wU + (v10.w * lxm + v11.w * lx) * wD;
        red[wave][pw][lane] = v;
    }
    __syncthreads();

    // 4-way max combine + fp16 store: 7*64 thread-items
    for (int idx = tid; idx < 448; idx += 256) {
        const int pw = idx >> 6, cg = idx & 63;
        const float4 a = red[0][pw][cg];
        const float4 b = red[1][pw][cg];
        const float4 c = red[2][pw][cg];
        const float4 d = red[3][pw][cg];
        union { _Float16 h[4]; uint2 v2; } pk;
        pk.h[0] = (_Float16)fmaxf(fmaxf(a.x, b.x), fmaxf(c.x, d.x));
        pk.h[1] = (_Float16)fmaxf(fmaxf(a.y, b.y), fmaxf(c.y, d.y));
        pk.h[2] = (_Float16)fmaxf(fmaxf(a.z, b.z), fmaxf(c.z, d.z));
        pk.h[3] = (_Float16)fmaxf(fmaxf(a.w, b.w), fmaxf(c.w, d.w));
        _Float16* outp = pooledH + (size_t)roi * PD + (ph * 7 + pw) * 256 + cg * 4;
        *reinterpret_cast<uint2*>(outp) = pk.v2;
    }
}

// ---------------------------------------------------------------------------
// W1 [12544][1024] fp32 -> W1T [1024][12544] fp16 (transposed, GEMM1
// k-permutation folded).
// ---------------------------------------------------------------------------
__global__ __launch_bounds__(256) void convert_w1_kernel(
    const float* __restrict__ W1, _Float16* __restrict__ W1T)
{
    __shared__ float tile[64][65];
    const int p0  = blockIdx.x * 64;
    const int n0  = blockIdx.y * 64;
    const int col = threadIdx.x & 63;
    const int r0  = threadIdx.x >> 6;
#pragma unroll
    for (int r = r0; r < 64; r += 4) {
        const int pp   = p0 + r;
        const int ksrc = (pp & 255) * 49 + (pp >> 8);
        tile[r][col] = W1[(size_t)ksrc * 1024 + n0 + col];
    }
    __syncthreads();
#pragma unroll
    for (int nr = r0; nr < 64; nr += 4)
        W1T[(size_t)(n0 + nr) * PD + p0 + col] = (_Float16)tile[col][nr];
}

// ---------------------------------------------------------------------------
// Merged: W2 -> W2T [1024][2048] (grid.y<16) and [Wloc|Wsc] -> WhT [512][2048]
// (both hi/lo bf16 interleaved)
// ---------------------------------------------------------------------------
__global__ __launch_bounds__(256) void convert_w2h_kernel(
    const float* __restrict__ W2, const float* __restrict__ Wloc,
    const float* __restrict__ Wsc, ushort2* __restrict__ W2T,
    ushort2* __restrict__ WhT)
{
    __shared__ float tile[64][65];
    const int p0  = blockIdx.x * 64;
    const int col = threadIdx.x & 63;
    const int r0  = threadIdx.x >> 6;

    if (blockIdx.y < 16) {
        const int n0 = blockIdx.y * 64;
#pragma unroll
        for (int r = r0; r < 64; r += 4)
            tile[r][col] = W2[(size_t)(p0 + r) * 1024 + n0 + col];
        __syncthreads();
#pragma unroll
        for (int nr = r0; nr < 64; nr += 4)
            W2T[(size_t)(n0 + nr) * 1024 + p0 + col] = split_hl(tile[col][nr]);
    } else {
        const int n0 = (blockIdx.y - 16) * 64;
#pragma unroll
        for (int r = r0; r < 64; r += 4) {
            const int pp = p0 + r;
            const int n  = n0 + col;
            float v = 0.0f;
            if (n < NLOC)    v = Wloc[(size_t)pp * NLOC + n];
            else if (n < NH) v = Wsc[(size_t)pp * NSC + (n - NLOC)];
            tile[r][col] = v;
        }
        __syncthreads();
#pragma unroll
        for (int nr = r0; nr < 64; nr += 4)
            WhT[(size_t)(n0 + nr) * 1024 + p0 + col] = split_hl(tile[col][nr]);
    }
}

// ---------------------------------------------------------------------------
// 16-bit MFMA GEMM (round-0 proven structure): tile 64(M)x128(N), BK=64,
// 4 waves, wave w owns rows [w*16,w*16+16) x all 128 cols (acc[8] of 16x16).
// global_load_lds width 16, XOR-swizzled LDS. grid = (splitK, N/128, M/64).
// 24 KB LDS, launch_bounds(256,4) -> 4 blocks/CU. K-steps distributed over
// gridDim.x via q/r partition. F16: fp16 single; else bf16 (hi/lo in data).
// partial[z][m][n], z-stride = (gridDim.z*64)*N.
// ---------------------------------------------------------------------------
template<bool F16>
__global__ __launch_bounds__(256, 4) void gemm_16b_kernel(
    const unsigned short* __restrict__ A,
    const unsigned short* __restrict__ B,
    float* __restrict__ partial,
    int K2, int N)
{
    __shared__ __align__(16) unsigned short As[64 * 64];    // 8 KB
    __shared__ __align__(16) unsigned short Bs[128 * 64];   // 16 KB

    const int tid  = threadIdx.x;
    const int lane = tid & 63;
    const int wave = tid >> 6;

    const int totalSteps = K2 >> 6;
    const int nz = gridDim.x;
    const int z  = blockIdx.x;
    const int q  = totalSteps / nz, r = totalSteps % nz;
    const int myStart = z * q + min(z, r);
    const int mySteps = q + (z < r ? 1 : 0);

    const int n0 = blockIdx.y * 128;
    const int m0 = blockIdx.z * 64;

    const int rIn  = lane >> 3;          // 0..7
    const int cSrc = (lane & 7) ^ rIn;   // XOR-swizzled source chunk

    const int mrow = lane & 15, quad = lane >> 4;

    floatx4 acc[8];
#pragma unroll
    for (int j = 0; j < 8; ++j)
        acc[j] = (floatx4){0.f, 0.f, 0.f, 0.f};

    for (int s = 0; s < mySteps; ++s) {
        const int k0 = (myStart + s) * 64;
        // stage A: wave w -> rows [w*16, w*16+16)
#pragma unroll
        for (int qq = 0; qq < 2; ++qq) {
            const int rowBase = wave * 16 + qq * 8;
            const unsigned short* ga =
                A + (size_t)(m0 + rowBase + rIn) * K2 + k0 + cSrc * 8;
            __builtin_amdgcn_global_load_lds(
                (const __attribute__((address_space(1))) void*)ga,
                (__attribute__((address_space(3))) void*)&As[rowBase * 64], 16, 0, 0);
        }
        // stage B: wave w -> rows [w*32, w*32+32)
#pragma unroll
        for (int qq = 0; qq < 4; ++qq) {
            const int rowBase = wave * 32 + qq * 8;
            const unsigned short* gb =
                B + (size_t)(n0 + rowBase + rIn) * K2 + k0 + cSrc * 8;
            __builtin_amdgcn_global_load_lds(
                (const __attribute__((address_space(1))) void*)gb,
                (__attribute__((address_space(3))) void*)&Bs[rowBase * 64], 16, 0, 0);
        }
        __syncthreads();

#pragma unroll
        for (int ks = 0; ks < 2; ++ks) {
            const int ra = wave * 16 + mrow;
            const int ca = ((ks * 4 + quad) ^ (ra & 7)) * 8;
#pragma unroll
            for (int j = 0; j < 8; ++j) {
                const int rb = j * 16 + mrow;
                const int cb = ((ks * 4 + quad) ^ (rb & 7)) * 8;
                if constexpr (F16) {
                    const f16x8 aF = *reinterpret_cast<const f16x8*>(&As[ra * 64 + ca]);
                    const f16x8 bF = *reinterpret_cast<const f16x8*>(&Bs[rb * 64 + cb]);
                    acc[j] = __builtin_amdgcn_mfma_f32_16x16x32_f16(aF, bF, acc[j], 0, 0, 0);
                } else {
                    const bf16x8 aF = *reinterpret_cast<const bf16x8*>(&As[ra * 64 + ca]);
                    const bf16x8 bF = *reinterpret_cast<const bf16x8*>(&Bs[rb * 64 + cb]);
                    acc[j] = __builtin_amdgcn_mfma_f32_16x16x32_bf16(aF, bF, acc[j], 0, 0, 0);
                }
            }
        }
        __syncthreads();
    }

    // C/D layout: col = lane&15, row = quad*4 + reg
    float* p = partial + (size_t)blockIdx.x * (size_t)(gridDim.z * 64) * N;
    const int row = m0 + wave * 16 + quad * 4;
#pragma unroll
    for (int j = 0; j < 8; ++j) {
        const int col = n0 + j * 16 + mrow;
#pragma unroll
        for (int rr = 0; rr < 4; ++rr)
            p[(size_t)(row + rr) * N + col] = acc[j][rr];
    }
}

// ---------------------------------------------------------------------------
// fc = relu(sum_z partial + bias) -> hi/lo bf16 interleaved. float4 path.
// ---------------------------------------------------------------------------
__global__ __launch_bounds__(256) void reduce_fc_kernel(
    const float* __restrict__ partial, const float* __restrict__ bias,
    ushort2* __restrict__ outHL, int nz)
{
    const int i4 = blockIdx.x * 256 + threadIdx.x;
    const int off = i4 * 4;
    const int m = off >> 10, n = off & 1023;
    float4 acc = *reinterpret_cast<const float4*>(partial + off);
    for (int z = 1; z < nz; ++z) {
        const float4 v = *reinterpret_cast<const float4*>(
            partial + (size_t)z * 1024 * 1024 + off);
        acc.x += v.x; acc.y += v.y; acc.z += v.z; acc.w += v.w;
    }
    const float4 bv = *reinterpret_cast<const float4*>(bias + n);
    ushort2* o = outHL + (size_t)m * 1024 + n;
    o[0] = split_hl(fmaxf(acc.x + bv.x, 0.f));
    o[1] = split_hl(fmaxf(acc.y + bv.y, 0.f));
    o[2] = split_hl(fmaxf(acc.z + bv.z, 0.f));
    o[3] = split_hl(fmaxf(acc.w + bv.w, 0.f));
}

// heads: sum partials [z][1024][512], add bias, split-store to out0/out1
__global__ __launch_bounds__(256) void reduce_heads_kernel(
    const float* __restrict__ partial, const float* __restrict__ bloc,
    const float* __restrict__ bsc, float* __restrict__ out0,
    float* __restrict__ out1, int nz)
{
    const int m = blockIdx.x;   // 0..999
    for (int n = threadIdx.x; n < NH; n += 256) {
        float s = 0.f;
        for (int z = 0; z < nz; ++z)
            s += partial[(size_t)z * 1024 * 512 + (size_t)m * 512 + n];
        if (n < NLOC) out0[(size_t)m * NLOC + n] = s + bloc[n];
        else          out1[(size_t)m * NSC + (n - NLOC)] = s + bsc[n - NLOC];
    }
}

// ---------------------------------------------------------------------------
extern "C" void kernel_launch(void* const* d_in, const int* in_sizes, int n_in,
                              void* d_out, int out_size, void* d_ws, size_t ws_size,
                              hipStream_t stream)
{
    const float* f2   = (const float*)d_in[0];
    const float* f3   = (const float*)d_in[1];
    const float* f4   = (const float*)d_in[2];
    const float* f5   = (const float*)d_in[3];
    const float* rois = (const float*)d_in[4];
    const int*   img  = (const int*)d_in[5];
    const float* W1   = (const float*)d_in[6];
    const float* b1   = (const float*)d_in[7];
    const float* W2   = (const float*)d_in[8];
    const float* b2   = (const float*)d_in[9];
    const float* Wloc = (const float*)d_in[10];
    const float* bloc = (const float*)d_in[11];
    const float* Wsc  = (const float*)d_in[12];
    const float* bsc  = (const float*)d_in[13];
    float* out = (float*)d_out;

    float* ws = (float*)d_ws;
    float*     fT     = ws;
    _Float16*  pooled = (_Float16*)(ws + OFF_POOL);
    _Float16*  w1t    = (_Float16*)(ws + OFF_W1T);    // over dead fT
    float*     part1  = ws + OFF_PART1;               // 8 slices, over dead fT
    float*     part2  = ws + OFF_PART2;               // over dead W1T
    ushort2*   w2t    = (ushort2*)(ws + OFF_W2T);
    ushort2*   wht    = (ushort2*)(ws + OFF_WHT);
    ushort2*   fc1    = (ushort2*)(ws + OFF_FC1);
    ushort2*   fc2    = (ushort2*)(ws + OFF_FC2);

    // 1) feature transpose to [pix][256], all levels fused
    transpose_feat_kernel<<<dim3(1360, 4), 256, 0, stream>>>(f2, f3, f4, f5, fT);

    // 2) ROI pool -> fp16 pooled
    roi_pool_kernel<<<dim3(NROIS, 7), 256, 0, stream>>>(fT, rois, img, pooled);

    // 3) weight conversions (W1T over dead fT; W2T/WhT in private region)
    convert_w1_kernel<<<dim3(196, 16), 256, 0, stream>>>(W1, w1t);
    convert_w2h_kernel<<<dim3(16, 23), 256, 0, stream>>>(W2, Wloc, Wsc, w2t, wht);

    // 4) fc1 = relu(pooled @ W1 + b1): fp16, K=12544, grid (8,8,16)=1024 blocks
    gemm_16b_kernel<true><<<dim3(8, 8, 16), 256, 0, stream>>>(
        (const unsigned short*)pooled, (const unsigned short*)w1t, part1,
        PD, 1024);
    reduce_fc_kernel<<<1024, 256, 0, stream>>>(part1, b1, fc1, 8);

    // 5) fc2 = relu(fc1 @ W2 + b2): bf16 hi/lo, grid (4,8,16)=512 blocks
    gemm_16b_kernel<false><<<dim3(4, 8, 16), 256, 0, stream>>>(
        (const unsigned short*)fc1, (const unsigned short*)w2t, part2,
        K2_2, 1024);
    reduce_fc_kernel<<<1024, 256, 0, stream>>>(part2, b2, fc2, 4);

    // 6) heads: N=512, grid (8,4,16)=512 blocks
    gemm_16b_kernel<false><<<dim3(8, 4, 16), 256, 0, stream>>>(
        (const unsigned short*)fc2, (const unsigned short*)wht, part2,
        K2_2, 512);
    reduce_heads_kernel<<<NROIS, 256, 0, stream>>>(
        part2, bloc, bsc, out, out + (size_t)NROIS * NLOC, 8);
}

// Round 7
// 317.164 us; speedup vs baseline: 1.2996x; 1.0819x over previous
//
#include <hip/hip_runtime.h>
#include <hip/hip_bf16.h>
#include <cstdint>
#include <cstddef>

typedef __bf16 bf16x8 __attribute__((ext_vector_type(8)));
typedef _Float16 f16x8 __attribute__((ext_vector_type(8)));
typedef _Float16 f16x4 __attribute__((ext_vector_type(4)));
typedef float floatx4 __attribute__((ext_vector_type(4)));

#define NROIS 1000
#define PD    12544   // 256*49 = fc1 K (fp16, single)
#define K2_2  2048    // 2*1024 (hi/lo interleaved) for fc2/heads
#define NLOC  324
#define NSC   81
#define NH    405

// ---- workspace layout v4 (float offsets), no live aliasing ----------------
// fT is fp16: 22,282,240 halves = 11,141,120 floats.
// OFF_T* are offsets in HALF units within fT.
#define OFF_T2    0u
#define OFF_T3    16777216u
#define OFF_T4    20971520u
#define OFF_T5    22020096u
#define OFF_FT    0u          // [0, 11,141,120) floats
#define OFF_POOL  11141120u   // pooled fp16: 6,422,528 floats -> ends 17,563,648
#define OFF_W1T   17563648u   // W1T fp16: 6,422,528 floats   -> ends 23,986,176
#define OFF_PART1 23986176u   // 8 x 1,048,576 fp32           -> ends 32,374,784
#define OFF_FC1   32374784u   // ushort2 1024x1024            -> ends 33,423,360
#define OFF_W2T   33423360u   //                              -> ends 34,471,936
#define OFF_WHT   34471936u   //                              -> ends 34,996,224
#define OFF_FC2   34996224u   //                              -> ends 36,044,800
#define OFF_PART2 23986176u   // over dead part1

// ---- bf16 hi/lo helpers ----------------------------------------------------
__device__ __forceinline__ unsigned short f2bf(float x) {
    unsigned int u = __float_as_uint(x);
    u = u + 0x7fffu + ((u >> 16) & 1u);          // RNE
    return (unsigned short)(u >> 16);
}
__device__ __forceinline__ float bf2f(unsigned short h) {
    return __uint_as_float(((unsigned int)h) << 16);
}
__device__ __forceinline__ ushort2 split_hl(float f) {
    const unsigned short hi = f2bf(f);
    const unsigned short lo = f2bf(f - bf2f(hi));
    return make_ushort2(hi, lo);
}
__device__ __forceinline__ unsigned int pack2h(float a, float b) {
    union { _Float16 h[2]; unsigned int u; } p;
    p.h[0] = (_Float16)a; p.h[1] = (_Float16)b;
    return p.u;
}

// ---------------------------------------------------------------------------
// Fused transpose of all 4 pyramid levels [256][P] fp32 -> [P][256] fp16.
// Packed 2-channel uint stores keep writes coalesced.
// ---------------------------------------------------------------------------
__global__ __launch_bounds__(256) void transpose_feat_kernel(
    const float* __restrict__ f2, const float* __restrict__ f3,
    const float* __restrict__ f4, const float* __restrict__ f5,
    _Float16* __restrict__ fT)
{
    __shared__ float tile[64][65];
    int bx = blockIdx.x;
    const float* src; _Float16* dst; int P;
    if (bx < 1024)      {            src = f2; dst = fT + OFF_T2; P = 65536; }
    else if (bx < 1280) { bx -= 1024; src = f3; dst = fT + OFF_T3; P = 16384; }
    else if (bx < 1344) { bx -= 1280; src = f4; dst = fT + OFF_T4; P = 4096; }
    else                { bx -= 1344; src = f5; dst = fT + OFF_T5; P = 1024; }

    const int p0  = bx * 64;
    const int c0  = blockIdx.y * 64;
    const int col = threadIdx.x & 63;
    const int r0  = threadIdx.x >> 6;
    // tile[channel][pixel]
#pragma unroll
    for (int r = r0; r < 64; r += 4)
        tile[r][col] = src[(size_t)(c0 + r) * P + p0 + col];
    __syncthreads();

    // store: thread -> (pixel r, channel pair c2)
    unsigned int* dstU = reinterpret_cast<unsigned int*>(dst);
    const int c2  = (threadIdx.x & 31) * 2;
    const int rr0 = threadIdx.x >> 5;          // 0..7
#pragma unroll
    for (int r = rr0; r < 64; r += 8)
        dstU[((size_t)(p0 + r) * 256 + c0 + c2) >> 1] =
            pack2h(tile[c2][r], tile[c2 + 1][r]);
}

// ---------------------------------------------------------------------------
// ROI align + 2x2 max, fp16 features in, fp16 pooled out.
// Block = (roi, ph), lane = 4-channel group (f16x4 loads),
// wave = (syy, sx parity); 4-way LDS max combine.
// ---------------------------------------------------------------------------
__global__ __launch_bounds__(256) void roi_pool_kernel(
    const _Float16* __restrict__ fT, const float* __restrict__ rois,
    const int* __restrict__ img_size, _Float16* __restrict__ pooledH)
{
    const int roi  = blockIdx.x;        // 0..999
    const int ph   = blockIdx.y;        // 0..6
    const int tid  = threadIdx.x;
    const int lane = tid & 63;
    const int wave = tid >> 6;
    const int syy  = wave >> 1;
    const int sxp  = wave & 1;

    const float y1 = rois[roi * 4 + 0];
    const float x1 = rois[roi * 4 + 1];
    const float y2 = rois[roi * 4 + 2];
    const float x2 = rois[roi * 4 + 3];

    const float hh = y2 - y1 + 1.0f;
    const float ww = x2 - x1 + 1.0f;
    float lvlf = floorf(logf(sqrtf(hh * ww) / 224.0f) / 0.693147f + 4.0f);
    lvlf = fminf(fmaxf(lvlf, 2.0f), 5.0f);
    const int lvl = (int)lvlf;

    const _Float16* f;
    int H;
    if (lvl == 2)      { f = fT + OFF_T2; H = 256; }
    else if (lvl == 3) { f = fT + OFF_T3; H = 128; }
    else if (lvl == 4) { f = fT + OFF_T4; H = 64;  }
    else               { f = fT + OFF_T5; H = 32;  }
    const int W = H;

    const float imh = (float)img_size[0] - 1.0f;
    const float imw = (float)img_size[1] - 1.0f;
    const float r0 = y1 * (float)(H - 1) / imh;
    const float r1 = x1 * (float)(W - 1) / imw;
    const float r2 = y2 * (float)(H - 1) / imh;
    const float r3 = x2 * (float)(W - 1) / imw;
    const float hs  = (r2 - r0) * (1.0f / 14.0f);
    const float wst = (r3 - r1) * (1.0f / 14.0f);

    const float cy = ((float)(ph * 2 + syy) + 0.5f) * hs + r0;
    const float fy = floorf(cy);
    int   iu  = (int)fy;
    int   idn = (int)ceilf(cy);
    const float ly = cy - fy;
    iu  = min(max(iu, 0),  H - 1);
    idn = min(max(idn, 0), H - 1);
    const float wU = 1.0f - ly, wD = ly;
    const f16x4* rowU = (const f16x4*)(f + (size_t)(iu  * W) * 256);
    const f16x4* rowD = (const f16x4*)(f + (size_t)(idn * W) * 256);

    __shared__ float4 red[4][7][64];    // 28 KB

#pragma unroll
    for (int pw = 0; pw < 7; ++pw) {
        const int sx = pw * 2 + sxp;
        const float cx = ((float)sx + 0.5f) * wst + r1;
        const float fx = floorf(cx);
        int   il = (int)fx;
        int   ir = (int)ceilf(cx);
        const float lx = cx - fx;
        il = min(max(il, 0), W - 1);
        ir = min(max(ir, 0), W - 1);

        const f16x4 h00 = rowU[il * 64 + lane];
        const f16x4 h01 = rowU[ir * 64 + lane];
        const f16x4 h10 = rowD[il * 64 + lane];
        const f16x4 h11 = rowD[ir * 64 + lane];
        const float lxm = 1.0f - lx;
        float4 v;
        v.x = ((float)h00.x * lxm + (float)h01.x * lx) * wU + ((float)h10.x * lxm + (float)h11.x * lx) * wD;
        v.y = ((float)h00.y * lxm + (float)h01.y * lx) * wU + ((float)h10.y * lxm + (float)h11.y * lx) * wD;
        v.z = ((float)h00.z * lxm + (float)h01.z * lx) * wU + ((float)h10.z * lxm + (float)h11.z * lx) * wD;
        v.w = ((float)h00.w * lxm + (float)h01.w * lx) * wU + ((float)h10.w * lxm + (float)h11.w * lx) * wD;
        red[wave][pw][lane] = v;
    }
    __syncthreads();

    // 4-way max combine + fp16 store: 7*64 thread-items
    for (int idx = tid; idx < 448; idx += 256) {
        const int pw = idx >> 6, cg = idx & 63;
        const float4 a = red[0][pw][cg];
        const float4 b = red[1][pw][cg];
        const float4 c = red[2][pw][cg];
        const float4 d = red[3][pw][cg];
        union { _Float16 h[4]; uint2 v2; } pk;
        pk.h[0] = (_Float16)fmaxf(fmaxf(a.x, b.x), fmaxf(c.x, d.x));
        pk.h[1] = (_Float16)fmaxf(fmaxf(a.y, b.y), fmaxf(c.y, d.y));
        pk.h[2] = (_Float16)fmaxf(fmaxf(a.z, b.z), fmaxf(c.z, d.z));
        pk.h[3] = (_Float16)fmaxf(fmaxf(a.w, b.w), fmaxf(c.w, d.w));
        _Float16* outp = pooledH + (size_t)roi * PD + (ph * 7 + pw) * 256 + cg * 4;
        *reinterpret_cast<uint2*>(outp) = pk.v2;
    }
}

// ---------------------------------------------------------------------------
// W1 [12544][1024] fp32 -> W1T [1024][12544] fp16 (transposed, GEMM1
// k-permutation folded). Packed uint stores.
// ---------------------------------------------------------------------------
__global__ __launch_bounds__(256) void convert_w1_kernel(
    const float* __restrict__ W1, _Float16* __restrict__ W1T)
{
    __shared__ float tile[64][65];
    const int p0  = blockIdx.x * 64;
    const int n0  = blockIdx.y * 64;
    const int col = threadIdx.x & 63;
    const int r0  = threadIdx.x >> 6;
    // tile[p][n]
#pragma unroll
    for (int r = r0; r < 64; r += 4) {
        const int pp   = p0 + r;
        const int ksrc = (pp & 255) * 49 + (pp >> 8);
        tile[r][col] = W1[(size_t)ksrc * 1024 + n0 + col];
    }
    __syncthreads();

    unsigned int* dstU = reinterpret_cast<unsigned int*>(W1T);
    const int c2  = (threadIdx.x & 31) * 2;    // p-pair within tile
    const int rr0 = threadIdx.x >> 5;          // 0..7
#pragma unroll
    for (int nr = rr0; nr < 64; nr += 8)
        dstU[((size_t)(n0 + nr) * PD + p0 + c2) >> 1] =
            pack2h(tile[c2][nr], tile[c2 + 1][nr]);
}

// ---------------------------------------------------------------------------
// Merged: W2 -> W2T [1024][2048] (grid.y<16) and [Wloc|Wsc] -> WhT [512][2048]
// (both hi/lo bf16 interleaved)
// ---------------------------------------------------------------------------
__global__ __launch_bounds__(256) void convert_w2h_kernel(
    const float* __restrict__ W2, const float* __restrict__ Wloc,
    const float* __restrict__ Wsc, ushort2* __restrict__ W2T,
    ushort2* __restrict__ WhT)
{
    __shared__ float tile[64][65];
    const int p0  = blockIdx.x * 64;
    const int col = threadIdx.x & 63;
    const int r0  = threadIdx.x >> 6;

    if (blockIdx.y < 16) {
        const int n0 = blockIdx.y * 64;
#pragma unroll
        for (int r = r0; r < 64; r += 4)
            tile[r][col] = W2[(size_t)(p0 + r) * 1024 + n0 + col];
        __syncthreads();
#pragma unroll
        for (int nr = r0; nr < 64; nr += 4)
            W2T[(size_t)(n0 + nr) * 1024 + p0 + col] = split_hl(tile[col][nr]);
    } else {
        const int n0 = (blockIdx.y - 16) * 64;
#pragma unroll
        for (int r = r0; r < 64; r += 4) {
            const int pp = p0 + r;
            const int n  = n0 + col;
            float v = 0.0f;
            if (n < NLOC)    v = Wloc[(size_t)pp * NLOC + n];
            else if (n < NH) v = Wsc[(size_t)pp * NSC + (n - NLOC)];
            tile[r][col] = v;
        }
        __syncthreads();
#pragma unroll
        for (int nr = r0; nr < 64; nr += 4)
            WhT[(size_t)(n0 + nr) * 1024 + p0 + col] = split_hl(tile[col][nr]);
    }
}

// ---------------------------------------------------------------------------
// 16-bit MFMA GEMM (round-0 proven structure): tile 64(M)x128(N), BK=64,
// 4 waves, wave w owns rows [w*16,w*16+16) x all 128 cols (acc[8] of 16x16).
// global_load_lds width 16, XOR-swizzled LDS. grid = (splitK, N/128, M/64).
// 24 KB LDS, launch_bounds(256,4) -> 4 blocks/CU. K-steps distributed over
// gridDim.x via q/r partition. F16: fp16 single; else bf16 (hi/lo in data).
// partial[z][m][n], z-stride = (gridDim.z*64)*N.
// ---------------------------------------------------------------------------
template<bool F16>
__global__ __launch_bounds__(256, 4) void gemm_16b_kernel(
    const unsigned short* __restrict__ A,
    const unsigned short* __restrict__ B,
    float* __restrict__ partial,
    int K2, int N)
{
    __shared__ __align__(16) unsigned short As[64 * 64];    // 8 KB
    __shared__ __align__(16) unsigned short Bs[128 * 64];   // 16 KB

    const int tid  = threadIdx.x;
    const int lane = tid & 63;
    const int wave = tid >> 6;

    const int totalSteps = K2 >> 6;
    const int nz = gridDim.x;
    const int z  = blockIdx.x;
    const int q  = totalSteps / nz, r = totalSteps % nz;
    const int myStart = z * q + min(z, r);
    const int mySteps = q + (z < r ? 1 : 0);

    const int n0 = blockIdx.y * 128;
    const int m0 = blockIdx.z * 64;

    const int rIn  = lane >> 3;          // 0..7
    const int cSrc = (lane & 7) ^ rIn;   // XOR-swizzled source chunk

    const int mrow = lane & 15, quad = lane >> 4;

    floatx4 acc[8];
#pragma unroll
    for (int j = 0; j < 8; ++j)
        acc[j] = (floatx4){0.f, 0.f, 0.f, 0.f};

    for (int s = 0; s < mySteps; ++s) {
        const int k0 = (myStart + s) * 64;
        // stage A: wave w -> rows [w*16, w*16+16)
#pragma unroll
        for (int qq = 0; qq < 2; ++qq) {
            const int rowBase = wave * 16 + qq * 8;
            const unsigned short* ga =
                A + (size_t)(m0 + rowBase + rIn) * K2 + k0 + cSrc * 8;
            __builtin_amdgcn_global_load_lds(
                (const __attribute__((address_space(1))) void*)ga,
                (__attribute__((address_space(3))) void*)&As[rowBase * 64], 16, 0, 0);
        }
        // stage B: wave w -> rows [w*32, w*32+32)
#pragma unroll
        for (int qq = 0; qq < 4; ++qq) {
            const int rowBase = wave * 32 + qq * 8;
            const unsigned short* gb =
                B + (size_t)(n0 + rowBase + rIn) * K2 + k0 + cSrc * 8;
            __builtin_amdgcn_global_load_lds(
                (const __attribute__((address_space(1))) void*)gb,
                (__attribute__((address_space(3))) void*)&Bs[rowBase * 64], 16, 0, 0);
        }
        __syncthreads();

#pragma unroll
        for (int ks = 0; ks < 2; ++ks) {
            const int ra = wave * 16 + mrow;
            const int ca = ((ks * 4 + quad) ^ (ra & 7)) * 8;
#pragma unroll
            for (int j = 0; j < 8; ++j) {
                const int rb = j * 16 + mrow;
                const int cb = ((ks * 4 + quad) ^ (rb & 7)) * 8;
                if constexpr (F16) {
                    const f16x8 aF = *reinterpret_cast<const f16x8*>(&As[ra * 64 + ca]);
                    const f16x8 bF = *reinterpret_cast<const f16x8*>(&Bs[rb * 64 + cb]);
                    acc[j] = __builtin_amdgcn_mfma_f32_16x16x32_f16(aF, bF, acc[j], 0, 0, 0);
                } else {
                    const bf16x8 aF = *reinterpret_cast<const bf16x8*>(&As[ra * 64 + ca]);
                    const bf16x8 bF = *reinterpret_cast<const bf16x8*>(&Bs[rb * 64 + cb]);
                    acc[j] = __builtin_amdgcn_mfma_f32_16x16x32_bf16(aF, bF, acc[j], 0, 0, 0);
                }
            }
        }
        __syncthreads();
    }

    // C/D layout: col = lane&15, row = quad*4 + reg
    float* p = partial + (size_t)blockIdx.x * (size_t)(gridDim.z * 64) * N;
    const int row = m0 + wave * 16 + quad * 4;
#pragma unroll
    for (int j = 0; j < 8; ++j) {
        const int col = n0 + j * 16 + mrow;
#pragma unroll
        for (int rr = 0; rr < 4; ++rr)
            p[(size_t)(row + rr) * N + col] = acc[j][rr];
    }
}

// ---------------------------------------------------------------------------
// fc = relu(sum_z partial + bias) -> hi/lo bf16 interleaved. float4 path.
// ---------------------------------------------------------------------------
__global__ __launch_bounds__(256) void reduce_fc_kernel(
    const float* __restrict__ partial, const float* __restrict__ bias,
    ushort2* __restrict__ outHL, int nz)
{
    const int i4 = blockIdx.x * 256 + threadIdx.x;
    const int off = i4 * 4;
    const int m = off >> 10, n = off & 1023;
    float4 acc = *reinterpret_cast<const float4*>(partial + off);
    for (int z = 1; z < nz; ++z) {
        const float4 v = *reinterpret_cast<const float4*>(
            partial + (size_t)z * 1024 * 1024 + off);
        acc.x += v.x; acc.y += v.y; acc.z += v.z; acc.w += v.w;
    }
    const float4 bv = *reinterpret_cast<const float4*>(bias + n);
    ushort2* o = outHL + (size_t)m * 1024 + n;
    o[0] = split_hl(fmaxf(acc.x + bv.x, 0.f));
    o[1] = split_hl(fmaxf(acc.y + bv.y, 0.f));
    o[2] = split_hl(fmaxf(acc.z + bv.z, 0.f));
    o[3] = split_hl(fmaxf(acc.w + bv.w, 0.f));
}

// heads: sum partials [z][1024][512], add bias, split-store to out0/out1
__global__ __launch_bounds__(256) void reduce_heads_kernel(
    const float* __restrict__ partial, const float* __restrict__ bloc,
    const float* __restrict__ bsc, float* __restrict__ out0,
    float* __restrict__ out1, int nz)
{
    const int m = blockIdx.x;   // 0..999
    for (int n = threadIdx.x; n < NH; n += 256) {
        float s = 0.f;
        for (int z = 0; z < nz; ++z)
            s += partial[(size_t)z * 1024 * 512 + (size_t)m * 512 + n];
        if (n < NLOC) out0[(size_t)m * NLOC + n] = s + bloc[n];
        else          out1[(size_t)m * NSC + (n - NLOC)] = s + bsc[n - NLOC];
    }
}

// ---------------------------------------------------------------------------
extern "C" void kernel_launch(void* const* d_in, const int* in_sizes, int n_in,
                              void* d_out, int out_size, void* d_ws, size_t ws_size,
                              hipStream_t stream)
{
    const float* f2   = (const float*)d_in[0];
    const float* f3   = (const float*)d_in[1];
    const float* f4   = (const float*)d_in[2];
    const float* f5   = (const float*)d_in[3];
    const float* rois = (const float*)d_in[4];
    const int*   img  = (const int*)d_in[5];
    const float* W1   = (const float*)d_in[6];
    const float* b1   = (const float*)d_in[7];
    const float* W2   = (const float*)d_in[8];
    const float* b2   = (const float*)d_in[9];
    const float* Wloc = (const float*)d_in[10];
    const float* bloc = (const float*)d_in[11];
    const float* Wsc  = (const float*)d_in[12];
    const float* bsc  = (const float*)d_in[13];
    float* out = (float*)d_out;

    float* ws = (float*)d_ws;
    _Float16*  fT     = (_Float16*)(ws + OFF_FT);
    _Float16*  pooled = (_Float16*)(ws + OFF_POOL);
    _Float16*  w1t    = (_Float16*)(ws + OFF_W1T);
    float*     part1  = ws + OFF_PART1;
    float*     part2  = ws + OFF_PART2;               // over dead part1
    ushort2*   w2t    = (ushort2*)(ws + OFF_W2T);
    ushort2*   wht    = (ushort2*)(ws + OFF_WHT);
    ushort2*   fc1    = (ushort2*)(ws + OFF_FC1);
    ushort2*   fc2    = (ushort2*)(ws + OFF_FC2);

    // 1) feature transpose to [pix][256] fp16, all levels fused
    transpose_feat_kernel<<<dim3(1360, 4), 256, 0, stream>>>(f2, f3, f4, f5, fT);

    // 2) ROI pool (fp16 in/out)
    roi_pool_kernel<<<dim3(NROIS, 7), 256, 0, stream>>>(fT, rois, img, pooled);

    // 3) weight conversions
    convert_w1_kernel<<<dim3(196, 16), 256, 0, stream>>>(W1, w1t);
    convert_w2h_kernel<<<dim3(16, 23), 256, 0, stream>>>(W2, Wloc, Wsc, w2t, wht);

    // 4) fc1 = relu(pooled @ W1 + b1): fp16, K=12544, grid (8,8,16)=1024 blocks
    gemm_16b_kernel<true><<<dim3(8, 8, 16), 256, 0, stream>>>(
        (const unsigned short*)pooled, (const unsigned short*)w1t, part1,
        PD, 1024);
    reduce_fc_kernel<<<1024, 256, 0, stream>>>(part1, b1, fc1, 8);

    // 5) fc2 = relu(fc1 @ W2 + b2): bf16 hi/lo, grid (4,8,16)=512 blocks
    gemm_16b_kernel<false><<<dim3(4, 8, 16), 256, 0, stream>>>(
        (const unsigned short*)fc1, (const unsigned short*)w2t, part2,
        K2_2, 1024);
    reduce_fc_kernel<<<1024, 256, 0, stream>>>(part2, b2, fc2, 4);

    // 6) heads: N=512, grid (8,4,16)=512 blocks
    gemm_16b_kernel<false><<<dim3(8, 4, 16), 256, 0, stream>>>(
        (const unsigned short*)fc2, (const unsigned short*)wht, part2,
        K2_2, 512);
    reduce_heads_kernel<<<NROIS, 256, 0, stream>>>(
        part2, bloc, bsc, out, out + (size_t)NROIS * NLOC, 8);
}

// Round 8
// 312.741 us; speedup vs baseline: 1.3180x; 1.0141x over previous
//
#include <hip/hip_runtime.h>
#include <hip/hip_bf16.h>
#include <cstdint>
#include <cstddef>

typedef __bf16 bf16x8 __attribute__((ext_vector_type(8)));
typedef _Float16 f16x8 __attribute__((ext_vector_type(8)));
typedef _Float16 f16x4 __attribute__((ext_vector_type(4)));
typedef float floatx4 __attribute__((ext_vector_type(4)));

#define NROIS 1000
#define PD    12544   // 256*49 = fc1 K (fp16, single)
#define K2_2  2048    // 2*1024 (hi/lo interleaved) for fc2/heads
#define NLOC  324
#define NSC   81
#define NH    405

// ---- workspace layout v4 (float offsets), no live aliasing ----------------
// fT is fp16: 22,282,240 halves = 11,141,120 floats.
// OFF_T* are offsets in HALF units within fT.
#define OFF_T2    0u
#define OFF_T3    16777216u
#define OFF_T4    20971520u
#define OFF_T5    22020096u
#define OFF_FT    0u          // [0, 11,141,120) floats
#define OFF_POOL  11141120u   // pooled fp16: 6,422,528 floats -> ends 17,563,648
#define OFF_W1T   17563648u   // W1T fp16: 6,422,528 floats   -> ends 23,986,176
#define OFF_PART1 23986176u   // 8 x 1,048,576 fp32           -> ends 32,374,784
#define OFF_FC1   32374784u   // ushort2 1024x1024            -> ends 33,423,360
#define OFF_W2T   33423360u   //                              -> ends 34,471,936
#define OFF_WHT   34471936u   //                              -> ends 34,996,224
#define OFF_FC2   34996224u   //                              -> ends 36,044,800
#define OFF_PART2 23986176u   // over dead part1

// ---- helpers ---------------------------------------------------------------
__device__ __forceinline__ unsigned short f2bf(float x) {
    unsigned int u = __float_as_uint(x);
    u = u + 0x7fffu + ((u >> 16) & 1u);          // RNE
    return (unsigned short)(u >> 16);
}
__device__ __forceinline__ float bf2f(unsigned short h) {
    return __uint_as_float(((unsigned int)h) << 16);
}
__device__ __forceinline__ ushort2 split_hl(float f) {
    const unsigned short hi = f2bf(f);
    const unsigned short lo = f2bf(f - bf2f(hi));
    return make_ushort2(hi, lo);
}

// ---------------------------------------------------------------------------
// Fused prep kernel: one launch covers
//   [0, 5440)      feature transpose  [256][P] fp32 -> [P][256] fp16
//   [5440, 8576)   W1 -> W1T fp16 (transposed, k-permutation folded)
//   [8576, 8944)   W2 -> W2T hi/lo  and  [Wloc|Wsc] -> WhT hi/lo
// All branches: 256 threads, <=16.6 KB LDS, block-uniform control flow.
// Loads are float4 (16B/lane); LDS write aliasing is 2-way (free).
// ---------------------------------------------------------------------------
__global__ __launch_bounds__(256) void prep_kernel(
    const float* __restrict__ f2, const float* __restrict__ f3,
    const float* __restrict__ f4, const float* __restrict__ f5,
    _Float16* __restrict__ fT,
    const float* __restrict__ W1, _Float16* __restrict__ W1T,
    const float* __restrict__ W2, const float* __restrict__ Wloc,
    const float* __restrict__ Wsc, ushort2* __restrict__ W2T,
    ushort2* __restrict__ WhT)
{
    __shared__ float tile[64][65];
    const int bid = blockIdx.x;
    const int tid = threadIdx.x;
    const int g4  = tid & 15;           // 4-element group
    const int pr  = tid >> 4;           // 0..15

    if (bid < 5440) {
        // ---- feature transpose ----
        int bx = bid % 1360;
        const int c0 = (bid / 1360) * 64;
        const float* src; _Float16* dst; int P;
        if (bx < 1024)      {            src = f2; dst = fT + OFF_T2; P = 65536; }
        else if (bx < 1280) { bx -= 1024; src = f3; dst = fT + OFF_T3; P = 16384; }
        else if (bx < 1344) { bx -= 1280; src = f4; dst = fT + OFF_T4; P = 4096; }
        else                { bx -= 1344; src = f5; dst = fT + OFF_T5; P = 1024; }
        const int p0 = bx * 64;

        // load: tile[channel][pixel], float4 along pixel
#pragma unroll
        for (int k = 0; k < 4; ++k) {
            const int ch = pr + k * 16;
            const float4 v = *reinterpret_cast<const float4*>(
                &src[(size_t)(c0 + ch) * P + p0 + g4 * 4]);
            tile[ch][g4 * 4 + 0] = v.x;
            tile[ch][g4 * 4 + 1] = v.y;
            tile[ch][g4 * 4 + 2] = v.z;
            tile[ch][g4 * 4 + 3] = v.w;
        }
        __syncthreads();

        // store: pixel-major, 4 channels packed per uint2
#pragma unroll
        for (int k = 0; k < 4; ++k) {
            const int px = pr + k * 16;
            union { _Float16 h[4]; uint2 u; } pk;
            pk.h[0] = (_Float16)tile[g4 * 4 + 0][px];
            pk.h[1] = (_Float16)tile[g4 * 4 + 1][px];
            pk.h[2] = (_Float16)tile[g4 * 4 + 2][px];
            pk.h[3] = (_Float16)tile[g4 * 4 + 3][px];
            *reinterpret_cast<uint2*>(&dst[(size_t)(p0 + px) * 256 + c0 + g4 * 4]) = pk.u;
        }
    } else if (bid < 8576) {
        // ---- W1 -> W1T fp16 ----
        const int v  = bid - 5440;
        const int p0 = (v % 196) * 64;
        const int n0 = (v / 196) * 64;

        // load: tile[p][n], float4 along n
#pragma unroll
        for (int k = 0; k < 4; ++k) {
            const int r    = pr + k * 16;
            const int pp   = p0 + r;
            const int ksrc = (pp & 255) * 49 + (pp >> 8);
            const float4 w = *reinterpret_cast<const float4*>(
                &W1[(size_t)ksrc * 1024 + n0 + g4 * 4]);
            tile[r][g4 * 4 + 0] = w.x;
            tile[r][g4 * 4 + 1] = w.y;
            tile[r][g4 * 4 + 2] = w.z;
            tile[r][g4 * 4 + 3] = w.w;
        }
        __syncthreads();

        // store: n-major, 4 p packed per uint2
#pragma unroll
        for (int k = 0; k < 4; ++k) {
            const int nr = pr + k * 16;
            union { _Float16 h[4]; uint2 u; } pk;
            pk.h[0] = (_Float16)tile[g4 * 4 + 0][nr];
            pk.h[1] = (_Float16)tile[g4 * 4 + 1][nr];
            pk.h[2] = (_Float16)tile[g4 * 4 + 2][nr];
            pk.h[3] = (_Float16)tile[g4 * 4 + 3][nr];
            *reinterpret_cast<uint2*>(&W1T[(size_t)(n0 + nr) * PD + p0 + g4 * 4]) = pk.u;
        }
    } else {
        // ---- W2 / heads conversion (hi/lo bf16) ----
        const int v  = bid - 8576;
        const int p0 = (v % 16) * 64;
        const int by = v / 16;          // 0..22
        const int col = tid & 63;
        const int r0  = tid >> 6;

        if (by < 16) {
            const int n0 = by * 64;
#pragma unroll
            for (int k = 0; k < 4; ++k) {
                const int r = pr + k * 16;
                const float4 w = *reinterpret_cast<const float4*>(
                    &W2[(size_t)(p0 + r) * 1024 + n0 + g4 * 4]);
                tile[r][g4 * 4 + 0] = w.x;
                tile[r][g4 * 4 + 1] = w.y;
                tile[r][g4 * 4 + 2] = w.z;
                tile[r][g4 * 4 + 3] = w.w;
            }
            __syncthreads();
#pragma unroll
            for (int nr = r0; nr < 64; nr += 4)
                W2T[(size_t)(n0 + nr) * 1024 + p0 + col] = split_hl(tile[col][nr]);
        } else {
            const int n0 = (by - 16) * 64;
#pragma unroll
            for (int r = r0; r < 64; r += 4) {
                const int pp = p0 + r;
                const int n  = n0 + col;
                float w = 0.0f;
                if (n < NLOC)    w = Wloc[(size_t)pp * NLOC + n];
                else if (n < NH) w = Wsc[(size_t)pp * NSC + (n - NLOC)];
                tile[r][col] = w;
            }
            __syncthreads();
#pragma unroll
            for (int nr = r0; nr < 64; nr += 4)
                WhT[(size_t)(n0 + nr) * 1024 + p0 + col] = split_hl(tile[col][nr]);
        }
    }
}

// ---------------------------------------------------------------------------
// ROI align + 2x2 max, fp16 features in, fp16 pooled out.
// Block = (roi, ph), lane = 4-channel group (f16x4 loads),
// wave = (syy, sx parity); 4-way LDS max combine.
// ---------------------------------------------------------------------------
__global__ __launch_bounds__(256) void roi_pool_kernel(
    const _Float16* __restrict__ fT, const float* __restrict__ rois,
    const int* __restrict__ img_size, _Float16* __restrict__ pooledH)
{
    const int roi  = blockIdx.x;        // 0..999
    const int ph   = blockIdx.y;        // 0..6
    const int tid  = threadIdx.x;
    const int lane = tid & 63;
    const int wave = tid >> 6;
    const int syy  = wave >> 1;
    const int sxp  = wave & 1;

    const float y1 = rois[roi * 4 + 0];
    const float x1 = rois[roi * 4 + 1];
    const float y2 = rois[roi * 4 + 2];
    const float x2 = rois[roi * 4 + 3];

    const float hh = y2 - y1 + 1.0f;
    const float ww = x2 - x1 + 1.0f;
    float lvlf = floorf(logf(sqrtf(hh * ww) / 224.0f) / 0.693147f + 4.0f);
    lvlf = fminf(fmaxf(lvlf, 2.0f), 5.0f);
    const int lvl = (int)lvlf;

    const _Float16* f;
    int H;
    if (lvl == 2)      { f = fT + OFF_T2; H = 256; }
    else if (lvl == 3) { f = fT + OFF_T3; H = 128; }
    else if (lvl == 4) { f = fT + OFF_T4; H = 64;  }
    else               { f = fT + OFF_T5; H = 32;  }
    const int W = H;

    const float imh = (float)img_size[0] - 1.0f;
    const float imw = (float)img_size[1] - 1.0f;
    const float r0 = y1 * (float)(H - 1) / imh;
    const float r1 = x1 * (float)(W - 1) / imw;
    const float r2 = y2 * (float)(H - 1) / imh;
    const float r3 = x2 * (float)(W - 1) / imw;
    const float hs  = (r2 - r0) * (1.0f / 14.0f);
    const float wst = (r3 - r1) * (1.0f / 14.0f);

    const float cy = ((float)(ph * 2 + syy) + 0.5f) * hs + r0;
    const float fy = floorf(cy);
    int   iu  = (int)fy;
    int   idn = (int)ceilf(cy);
    const float ly = cy - fy;
    iu  = min(max(iu, 0),  H - 1);
    idn = min(max(idn, 0), H - 1);
    const float wU = 1.0f - ly, wD = ly;
    const f16x4* rowU = (const f16x4*)(f + (size_t)(iu  * W) * 256);
    const f16x4* rowD = (const f16x4*)(f + (size_t)(idn * W) * 256);

    __shared__ float4 red[4][7][64];    // 28 KB

#pragma unroll
    for (int pw = 0; pw < 7; ++pw) {
        const int sx = pw * 2 + sxp;
        const float cx = ((float)sx + 0.5f) * wst + r1;
        const float fx = floorf(cx);
        int   il = (int)fx;
        int   ir = (int)ceilf(cx);
        const float lx = cx - fx;
        il = min(max(il, 0), W - 1);
        ir = min(max(ir, 0), W - 1);

        const f16x4 h00 = rowU[il * 64 + lane];
        const f16x4 h01 = rowU[ir * 64 + lane];
        const f16x4 h10 = rowD[il * 64 + lane];
        const f16x4 h11 = rowD[ir * 64 + lane];
        const float lxm = 1.0f - lx;
        float4 v;
        v.x = ((float)h00.x * lxm + (float)h01.x * lx) * wU + ((float)h10.x * lxm + (float)h11.x * lx) * wD;
        v.y = ((float)h00.y * lxm + (float)h01.y * lx) * wU + ((float)h10.y * lxm + (float)h11.y * lx) * wD;
        v.z = ((float)h00.z * lxm + (float)h01.z * lx) * wU + ((float)h10.z * lxm + (float)h11.z * lx) * wD;
        v.w = ((float)h00.w * lxm + (float)h01.w * lx) * wU + ((float)h10.w * lxm + (float)h11.w * lx) * wD;
        red[wave][pw][lane] = v;
    }
    __syncthreads();

    // 4-way max combine + fp16 store: 7*64 thread-items
    for (int idx = tid; idx < 448; idx += 256) {
        const int pw = idx >> 6, cg = idx & 63;
        const float4 a = red[0][pw][cg];
        const float4 b = red[1][pw][cg];
        const float4 c = red[2][pw][cg];
        const float4 d = red[3][pw][cg];
        union { _Float16 h[4]; uint2 v2; } pk;
        pk.h[0] = (_Float16)fmaxf(fmaxf(a.x, b.x), fmaxf(c.x, d.x));
        pk.h[1] = (_Float16)fmaxf(fmaxf(a.y, b.y), fmaxf(c.y, d.y));
        pk.h[2] = (_Float16)fmaxf(fmaxf(a.z, b.z), fmaxf(c.z, d.z));
        pk.h[3] = (_Float16)fmaxf(fmaxf(a.w, b.w), fmaxf(c.w, d.w));
        _Float16* outp = pooledH + (size_t)roi * PD + (ph * 7 + pw) * 256 + cg * 4;
        *reinterpret_cast<uint2*>(outp) = pk.v2;
    }
}

// ---------------------------------------------------------------------------
// 16-bit MFMA GEMM (round-0 proven structure): tile 64(M)x128(N), BK=64,
// 4 waves, wave w owns rows [w*16,w*16+16) x all 128 cols (acc[8] of 16x16).
// global_load_lds width 16, XOR-swizzled LDS. grid = (splitK, N/128, M/64).
// 24 KB LDS, launch_bounds(256,4) -> 4 blocks/CU. K-steps distributed over
// gridDim.x via q/r partition. F16: fp16 single; else bf16 (hi/lo in data).
// partial[z][m][n], z-stride = (gridDim.z*64)*N.
// ---------------------------------------------------------------------------
template<bool F16>
__global__ __launch_bounds__(256, 4) void gemm_16b_kernel(
    const unsigned short* __restrict__ A,
    const unsigned short* __restrict__ B,
    float* __restrict__ partial,
    int K2, int N)
{
    __shared__ __align__(16) unsigned short As[64 * 64];    // 8 KB
    __shared__ __align__(16) unsigned short Bs[128 * 64];   // 16 KB

    const int tid  = threadIdx.x;
    const int lane = tid & 63;
    const int wave = tid >> 6;

    const int totalSteps = K2 >> 6;
    const int nz = gridDim.x;
    const int z  = blockIdx.x;
    const int q  = totalSteps / nz, r = totalSteps % nz;
    const int myStart = z * q + min(z, r);
    const int mySteps = q + (z < r ? 1 : 0);

    const int n0 = blockIdx.y * 128;
    const int m0 = blockIdx.z * 64;

    const int rIn  = lane >> 3;          // 0..7
    const int cSrc = (lane & 7) ^ rIn;   // XOR-swizzled source chunk

    const int mrow = lane & 15, quad = lane >> 4;

    floatx4 acc[8];
#pragma unroll
    for (int j = 0; j < 8; ++j)
        acc[j] = (floatx4){0.f, 0.f, 0.f, 0.f};

    for (int s = 0; s < mySteps; ++s) {
        const int k0 = (myStart + s) * 64;
        // stage A: wave w -> rows [w*16, w*16+16)
#pragma unroll
        for (int qq = 0; qq < 2; ++qq) {
            const int rowBase = wave * 16 + qq * 8;
            const unsigned short* ga =
                A + (size_t)(m0 + rowBase + rIn) * K2 + k0 + cSrc * 8;
            __builtin_amdgcn_global_load_lds(
                (const __attribute__((address_space(1))) void*)ga,
                (__attribute__((address_space(3))) void*)&As[rowBase * 64], 16, 0, 0);
        }
        // stage B: wave w -> rows [w*32, w*32+32)
#pragma unroll
        for (int qq = 0; qq < 4; ++qq) {
            const int rowBase = wave * 32 + qq * 8;
            const unsigned short* gb =
                B + (size_t)(n0 + rowBase + rIn) * K2 + k0 + cSrc * 8;
            __builtin_amdgcn_global_load_lds(
                (const __attribute__((address_space(1))) void*)gb,
                (__attribute__((address_space(3))) void*)&Bs[rowBase * 64], 16, 0, 0);
        }
        __syncthreads();

#pragma unroll
        for (int ks = 0; ks < 2; ++ks) {
            const int ra = wave * 16 + mrow;
            const int ca = ((ks * 4 + quad) ^ (ra & 7)) * 8;
#pragma unroll
            for (int j = 0; j < 8; ++j) {
                const int rb = j * 16 + mrow;
                const int cb = ((ks * 4 + quad) ^ (rb & 7)) * 8;
                if constexpr (F16) {
                    const f16x8 aF = *reinterpret_cast<const f16x8*>(&As[ra * 64 + ca]);
                    const f16x8 bF = *reinterpret_cast<const f16x8*>(&Bs[rb * 64 + cb]);
                    acc[j] = __builtin_amdgcn_mfma_f32_16x16x32_f16(aF, bF, acc[j], 0, 0, 0);
                } else {
                    const bf16x8 aF = *reinterpret_cast<const bf16x8*>(&As[ra * 64 + ca]);
                    const bf16x8 bF = *reinterpret_cast<const bf16x8*>(&Bs[rb * 64 + cb]);
                    acc[j] = __builtin_amdgcn_mfma_f32_16x16x32_bf16(aF, bF, acc[j], 0, 0, 0);
                }
            }
        }
        __syncthreads();
    }

    // C/D layout: col = lane&15, row = quad*4 + reg
    float* p = partial + (size_t)blockIdx.x * (size_t)(gridDim.z * 64) * N;
    const int row = m0 + wave * 16 + quad * 4;
#pragma unroll
    for (int j = 0; j < 8; ++j) {
        const int col = n0 + j * 16 + mrow;
#pragma unroll
        for (int rr = 0; rr < 4; ++rr)
            p[(size_t)(row + rr) * N + col] = acc[j][rr];
    }
}

// ---------------------------------------------------------------------------
// fc = relu(sum_z partial + bias) -> hi/lo bf16 interleaved. float4 path.
// ---------------------------------------------------------------------------
__global__ __launch_bounds__(256) void reduce_fc_kernel(
    const float* __restrict__ partial, const float* __restrict__ bias,
    ushort2* __restrict__ outHL, int nz)
{
    const int i4 = blockIdx.x * 256 + threadIdx.x;
    const int off = i4 * 4;
    const int m = off >> 10, n = off & 1023;
    float4 acc = *reinterpret_cast<const float4*>(partial + off);
    for (int z = 1; z < nz; ++z) {
        const float4 v = *reinterpret_cast<const float4*>(
            partial + (size_t)z * 1024 * 1024 + off);
        acc.x += v.x; acc.y += v.y; acc.z += v.z; acc.w += v.w;
    }
    const float4 bv = *reinterpret_cast<const float4*>(bias + n);
    ushort2* o = outHL + (size_t)m * 1024 + n;
    o[0] = split_hl(fmaxf(acc.x + bv.x, 0.f));
    o[1] = split_hl(fmaxf(acc.y + bv.y, 0.f));
    o[2] = split_hl(fmaxf(acc.z + bv.z, 0.f));
    o[3] = split_hl(fmaxf(acc.w + bv.w, 0.f));
}

// heads: sum partials [z][1024][512], add bias, split-store to out0/out1
__global__ __launch_bounds__(256) void reduce_heads_kernel(
    const float* __restrict__ partial, const float* __restrict__ bloc,
    const float* __restrict__ bsc, float* __restrict__ out0,
    float* __restrict__ out1, int nz)
{
    const int m = blockIdx.x;   // 0..999
    for (int n = threadIdx.x; n < NH; n += 256) {
        float s = 0.f;
        for (int z = 0; z < nz; ++z)
            s += partial[(size_t)z * 1024 * 512 + (size_t)m * 512 + n];
        if (n < NLOC) out0[(size_t)m * NLOC + n] = s + bloc[n];
        else          out1[(size_t)m * NSC + (n - NLOC)] = s + bsc[n - NLOC];
    }
}

// ---------------------------------------------------------------------------
extern "C" void kernel_launch(void* const* d_in, const int* in_sizes, int n_in,
                              void* d_out, int out_size, void* d_ws, size_t ws_size,
                              hipStream_t stream)
{
    const float* f2   = (const float*)d_in[0];
    const float* f3   = (const float*)d_in[1];
    const float* f4   = (const float*)d_in[2];
    const float* f5   = (const float*)d_in[3];
    const float* rois = (const float*)d_in[4];
    const int*   img  = (const int*)d_in[5];
    const float* W1   = (const float*)d_in[6];
    const float* b1   = (const float*)d_in[7];
    const float* W2   = (const float*)d_in[8];
    const float* b2   = (const float*)d_in[9];
    const float* Wloc = (const float*)d_in[10];
    const float* bloc = (const float*)d_in[11];
    const float* Wsc  = (const float*)d_in[12];
    const float* bsc  = (const float*)d_in[13];
    float* out = (float*)d_out;

    float* ws = (float*)d_ws;
    _Float16*  fT     = (_Float16*)(ws + OFF_FT);
    _Float16*  pooled = (_Float16*)(ws + OFF_POOL);
    _Float16*  w1t    = (_Float16*)(ws + OFF_W1T);
    float*     part1  = ws + OFF_PART1;
    float*     part2  = ws + OFF_PART2;               // over dead part1
    ushort2*   w2t    = (ushort2*)(ws + OFF_W2T);
    ushort2*   wht    = (ushort2*)(ws + OFF_WHT);
    ushort2*   fc1    = (ushort2*)(ws + OFF_FC1);
    ushort2*   fc2    = (ushort2*)(ws + OFF_FC2);

    // 1) fused prep: feature transpose + W1/W2/heads weight conversion
    prep_kernel<<<dim3(8944), 256, 0, stream>>>(
        f2, f3, f4, f5, fT, W1, w1t, W2, Wloc, Wsc, w2t, wht);

    // 2) ROI pool (fp16 in/out)
    roi_pool_kernel<<<dim3(NROIS, 7), 256, 0, stream>>>(fT, rois, img, pooled);

    // 3) fc1 = relu(pooled @ W1 + b1): fp16, K=12544, grid (8,8,16)=1024 blocks
    gemm_16b_kernel<true><<<dim3(8, 8, 16), 256, 0, stream>>>(
        (const unsigned short*)pooled, (const unsigned short*)w1t, part1,
        PD, 1024);
    reduce_fc_kernel<<<1024, 256, 0, stream>>>(part1, b1, fc1, 8);

    // 4) fc2 = relu(fc1 @ W2 + b2): bf16 hi/lo, grid (4,8,16)=512 blocks
    gemm_16b_kernel<false><<<dim3(4, 8, 16), 256, 0, stream>>>(
        (const unsigned short*)fc1, (const unsigned short*)w2t, part2,
        K2_2, 1024);
    reduce_fc_kernel<<<1024, 256, 0, stream>>>(part2, b2, fc2, 4);

    // 5) heads: N=512, grid (8,4,16)=512 blocks
    gemm_16b_kernel<false><<<dim3(8, 4, 16), 256, 0, stream>>>(
        (const unsigned short*)fc2, (const unsigned short*)wht, part2,
        K2_2, 512);
    reduce_heads_kernel<<<NROIS, 256, 0, stream>>>(
        part2, bloc, bsc, out, out + (size_t)NROIS * NLOC, 8);
}

// Round 9
// 306.494 us; speedup vs baseline: 1.3449x; 1.0204x over previous
//
#include <hip/hip_runtime.h>
#include <hip/hip_bf16.h>
#include <cstdint>
#include <cstddef>

typedef _Float16 f16x8 __attribute__((ext_vector_type(8)));
typedef _Float16 f16x4 __attribute__((ext_vector_type(4)));
typedef float floatx4 __attribute__((ext_vector_type(4)));

#define NROIS 1000
#define PD    12544   // 256*49 = fc1 K
#define KFC   1024    // fc2/heads K (fp16 single)
#define NLOC  324
#define NSC   81
#define NH    405

// ---- workspace layout v5 (float offsets), no live aliasing ----------------
// fT fp16 [0, 11,141,120) ; pooled fp16 [11,141,120, 17,563,648)
// W1T fp16 [17,563,648, 23,986,176) ; part1 [23,986,176, 32,374,784) (8 slices)
// fc1 fp16 [32,374,784, 32,899,072) ; W2T fp16 [32,899,072, 33,423,360)
// WhT fp16 [33,423,360, 33,685,504) ; fc2 fp16 [33,685,504, 34,209,792)
// part2 over dead part1 (fc2: 4 slices, heads: 8 x 512K) = max 4.2M floats
#define OFF_T2    0u          // half-units within fT
#define OFF_T3    16777216u
#define OFF_T4    20971520u
#define OFF_T5    22020096u
#define OFF_FT    0u
#define OFF_POOL  11141120u
#define OFF_W1T   17563648u
#define OFF_PART1 23986176u
#define OFF_FC1   32374784u
#define OFF_W2T   32899072u
#define OFF_WHT   33423360u
#define OFF_FC2   33685504u
#define OFF_PART2 23986176u

// ---------------------------------------------------------------------------
// Feature transpose [256][P] fp32 -> [P][256] fp16, 1-D grid 5440.
// ---------------------------------------------------------------------------
__global__ __launch_bounds__(256) void transpose_feat_kernel(
    const float* __restrict__ f2, const float* __restrict__ f3,
    const float* __restrict__ f4, const float* __restrict__ f5,
    _Float16* __restrict__ fT)
{
    __shared__ float tile[64][65];
    const int tid = threadIdx.x;
    const int g4  = tid & 15;
    const int pr  = tid >> 4;

    int bx = blockIdx.x % 1360;
    const int c0 = (blockIdx.x / 1360) * 64;
    const float* src; _Float16* dst; int P;
    if (bx < 1024)      {            src = f2; dst = fT + OFF_T2; P = 65536; }
    else if (bx < 1280) { bx -= 1024; src = f3; dst = fT + OFF_T3; P = 16384; }
    else if (bx < 1344) { bx -= 1280; src = f4; dst = fT + OFF_T4; P = 4096; }
    else                { bx -= 1344; src = f5; dst = fT + OFF_T5; P = 1024; }
    const int p0 = bx * 64;

#pragma unroll
    for (int k = 0; k < 4; ++k) {
        const int ch = pr + k * 16;
        const float4 v = *reinterpret_cast<const float4*>(
            &src[(size_t)(c0 + ch) * P + p0 + g4 * 4]);
        tile[ch][g4 * 4 + 0] = v.x;
        tile[ch][g4 * 4 + 1] = v.y;
        tile[ch][g4 * 4 + 2] = v.z;
        tile[ch][g4 * 4 + 3] = v.w;
    }
    __syncthreads();
#pragma unroll
    for (int k = 0; k < 4; ++k) {
        const int px = pr + k * 16;
        union { _Float16 h[4]; uint2 u; } pk;
        pk.h[0] = (_Float16)tile[g4 * 4 + 0][px];
        pk.h[1] = (_Float16)tile[g4 * 4 + 1][px];
        pk.h[2] = (_Float16)tile[g4 * 4 + 2][px];
        pk.h[3] = (_Float16)tile[g4 * 4 + 3][px];
        *reinterpret_cast<uint2*>(&dst[(size_t)(p0 + px) * 256 + c0 + g4 * 4]) = pk.u;
    }
}

// ---------------------------------------------------------------------------
// Fused: ROI pool + all weight conversions (independent work overlapped in
// one launch; weight blocks hide under roi_pool's memory latency).
//   [0, 7000)        roi_pool (roi = b/7, ph = b%7)
//   [7000, 10136)    W1 -> W1T fp16 (196 x 16)
//   [10136, 10392)   W2 -> W2T fp16 (16 x 16)
//   [10392, 10520)   [Wloc|Wsc] -> WhT fp16 (16 x 8)
// LDS: union, max 28 KB.
// ---------------------------------------------------------------------------
__global__ __launch_bounds__(256) void pool_prep_kernel(
    const _Float16* __restrict__ fT, const float* __restrict__ rois,
    const int* __restrict__ img_size, _Float16* __restrict__ pooledH,
    const float* __restrict__ W1, _Float16* __restrict__ W1T,
    const float* __restrict__ W2, const float* __restrict__ Wloc,
    const float* __restrict__ Wsc, _Float16* __restrict__ W2T,
    _Float16* __restrict__ WhT)
{
    __shared__ __align__(16) char smem[28672];
    const int bid = blockIdx.x;
    const int tid = threadIdx.x;

    if (bid < 7000) {
        // ---------------- ROI pool ----------------
        const int roi  = bid / 7;
        const int ph   = bid % 7;
        const int lane = tid & 63;
        const int wave = tid >> 6;
        const int syy  = wave >> 1;
        const int sxp  = wave & 1;

        const float y1 = rois[roi * 4 + 0];
        const float x1 = rois[roi * 4 + 1];
        const float y2 = rois[roi * 4 + 2];
        const float x2 = rois[roi * 4 + 3];

        const float hh = y2 - y1 + 1.0f;
        const float ww = x2 - x1 + 1.0f;
        float lvlf = floorf(logf(sqrtf(hh * ww) / 224.0f) / 0.693147f + 4.0f);
        lvlf = fminf(fmaxf(lvlf, 2.0f), 5.0f);
        const int lvl = (int)lvlf;

        const _Float16* f;
        int H;
        if (lvl == 2)      { f = fT + OFF_T2; H = 256; }
        else if (lvl == 3) { f = fT + OFF_T3; H = 128; }
        else if (lvl == 4) { f = fT + OFF_T4; H = 64;  }
        else               { f = fT + OFF_T5; H = 32;  }
        const int W = H;

        const float imh = (float)img_size[0] - 1.0f;
        const float imw = (float)img_size[1] - 1.0f;
        const float r0 = y1 * (float)(H - 1) / imh;
        const float r1 = x1 * (float)(W - 1) / imw;
        const float r2 = y2 * (float)(H - 1) / imh;
        const float r3 = x2 * (float)(W - 1) / imw;
        const float hs  = (r2 - r0) * (1.0f / 14.0f);
        const float wst = (r3 - r1) * (1.0f / 14.0f);

        const float cy = ((float)(ph * 2 + syy) + 0.5f) * hs + r0;
        const float fy = floorf(cy);
        int   iu  = (int)fy;
        int   idn = (int)ceilf(cy);
        const float ly = cy - fy;
        iu  = min(max(iu, 0),  H - 1);
        idn = min(max(idn, 0), H - 1);
        const float wU = 1.0f - ly, wD = ly;
        const f16x4* rowU = (const f16x4*)(f + (size_t)(iu  * W) * 256);
        const f16x4* rowD = (const f16x4*)(f + (size_t)(idn * W) * 256);

        float4 (*red)[7][64] = reinterpret_cast<float4 (*)[7][64]>(smem);  // 28 KB

#pragma unroll
        for (int pw = 0; pw < 7; ++pw) {
            const int sx = pw * 2 + sxp;
            const float cx = ((float)sx + 0.5f) * wst + r1;
            const float fx = floorf(cx);
            int   il = (int)fx;
            int   ir = (int)ceilf(cx);
            const float lx = cx - fx;
            il = min(max(il, 0), W - 1);
            ir = min(max(ir, 0), W - 1);

            const f16x4 h00 = rowU[il * 64 + lane];
            const f16x4 h01 = rowU[ir * 64 + lane];
            const f16x4 h10 = rowD[il * 64 + lane];
            const f16x4 h11 = rowD[ir * 64 + lane];
            const float lxm = 1.0f - lx;
            float4 v;
            v.x = ((float)h00.x * lxm + (float)h01.x * lx) * wU + ((float)h10.x * lxm + (float)h11.x * lx) * wD;
            v.y = ((float)h00.y * lxm + (float)h01.y * lx) * wU + ((float)h10.y * lxm + (float)h11.y * lx) * wD;
            v.z = ((float)h00.z * lxm + (float)h01.z * lx) * wU + ((float)h10.z * lxm + (float)h11.z * lx) * wD;
            v.w = ((float)h00.w * lxm + (float)h01.w * lx) * wU + ((float)h10.w * lxm + (float)h11.w * lx) * wD;
            red[wave][pw][lane] = v;
        }
        __syncthreads();

        for (int idx = tid; idx < 448; idx += 256) {
            const int pw = idx >> 6, cg = idx & 63;
            const float4 a = red[0][pw][cg];
            const float4 b = red[1][pw][cg];
            const float4 c = red[2][pw][cg];
            const float4 d = red[3][pw][cg];
            union { _Float16 h[4]; uint2 v2; } pk;
            pk.h[0] = (_Float16)fmaxf(fmaxf(a.x, b.x), fmaxf(c.x, d.x));
            pk.h[1] = (_Float16)fmaxf(fmaxf(a.y, b.y), fmaxf(c.y, d.y));
            pk.h[2] = (_Float16)fmaxf(fmaxf(a.z, b.z), fmaxf(c.z, d.z));
            pk.h[3] = (_Float16)fmaxf(fmaxf(a.w, b.w), fmaxf(c.w, d.w));
            _Float16* outp = pooledH + (size_t)roi * PD + (ph * 7 + pw) * 256 + cg * 4;
            *reinterpret_cast<uint2*>(outp) = pk.v2;
        }
    } else {
        // ---------------- weight conversions ----------------
        float (*tile)[65] = reinterpret_cast<float (*)[65]>(smem);        // 16.6 KB
        const int g4 = tid & 15;
        const int pr = tid >> 4;

        if (bid < 10136) {
            // W1 -> W1T fp16 (k-permutation folded)
            const int v  = bid - 7000;
            const int p0 = (v % 196) * 64;
            const int n0 = (v / 196) * 64;
#pragma unroll
            for (int k = 0; k < 4; ++k) {
                const int r    = pr + k * 16;
                const int pp   = p0 + r;
                const int ksrc = (pp & 255) * 49 + (pp >> 8);
                const float4 w = *reinterpret_cast<const float4*>(
                    &W1[(size_t)ksrc * 1024 + n0 + g4 * 4]);
                tile[r][g4 * 4 + 0] = w.x;
                tile[r][g4 * 4 + 1] = w.y;
                tile[r][g4 * 4 + 2] = w.z;
                tile[r][g4 * 4 + 3] = w.w;
            }
            __syncthreads();
#pragma unroll
            for (int k = 0; k < 4; ++k) {
                const int nr = pr + k * 16;
                union { _Float16 h[4]; uint2 u; } pk;
                pk.h[0] = (_Float16)tile[g4 * 4 + 0][nr];
                pk.h[1] = (_Float16)tile[g4 * 4 + 1][nr];
                pk.h[2] = (_Float16)tile[g4 * 4 + 2][nr];
                pk.h[3] = (_Float16)tile[g4 * 4 + 3][nr];
                *reinterpret_cast<uint2*>(&W1T[(size_t)(n0 + nr) * PD + p0 + g4 * 4]) = pk.u;
            }
        } else if (bid < 10392) {
            // W2 [1024 k][1024 n] -> W2T [n][k] fp16
            const int v  = bid - 10136;
            const int p0 = (v % 16) * 64;   // k block
            const int n0 = (v / 16) * 64;   // n block
#pragma unroll
            for (int k = 0; k < 4; ++k) {
                const int r = pr + k * 16;
                const float4 w = *reinterpret_cast<const float4*>(
                    &W2[(size_t)(p0 + r) * 1024 + n0 + g4 * 4]);
                tile[r][g4 * 4 + 0] = w.x;
                tile[r][g4 * 4 + 1] = w.y;
                tile[r][g4 * 4 + 2] = w.z;
                tile[r][g4 * 4 + 3] = w.w;
            }
            __syncthreads();
#pragma unroll
            for (int k = 0; k < 4; ++k) {
                const int nr = pr + k * 16;
                union { _Float16 h[4]; uint2 u; } pk;
                pk.h[0] = (_Float16)tile[g4 * 4 + 0][nr];
                pk.h[1] = (_Float16)tile[g4 * 4 + 1][nr];
                pk.h[2] = (_Float16)tile[g4 * 4 + 2][nr];
                pk.h[3] = (_Float16)tile[g4 * 4 + 3][nr];
                *reinterpret_cast<uint2*>(&W2T[(size_t)(n0 + nr) * KFC + p0 + g4 * 4]) = pk.u;
            }
        } else {
            // [Wloc|Wsc] -> WhT [512 n][1024 k] fp16
            const int v  = bid - 10392;
            const int p0 = (v % 16) * 64;   // k block
            const int n0 = (v / 16) * 64;   // n block (0..7 -> 512)
            const int col = tid & 63;
            const int r0  = tid >> 6;
#pragma unroll
            for (int r = r0; r < 64; r += 4) {
                const int pp = p0 + r;
                const int n  = n0 + col;
                float w = 0.0f;
                if (n < NLOC)    w = Wloc[(size_t)pp * NLOC + n];
                else if (n < NH) w = Wsc[(size_t)pp * NSC + (n - NLOC)];
                tile[r][col] = w;
            }
            __syncthreads();
#pragma unroll
            for (int k = 0; k < 4; ++k) {
                const int nr = pr + k * 16;
                union { _Float16 h[4]; uint2 u; } pk;
                pk.h[0] = (_Float16)tile[g4 * 4 + 0][nr];
                pk.h[1] = (_Float16)tile[g4 * 4 + 1][nr];
                pk.h[2] = (_Float16)tile[g4 * 4 + 2][nr];
                pk.h[3] = (_Float16)tile[g4 * 4 + 3][nr];
                *reinterpret_cast<uint2*>(&WhT[(size_t)(n0 + nr) * KFC + p0 + g4 * 4]) = pk.u;
            }
        }
    }
}

// ---------------------------------------------------------------------------
// fp16 MFMA GEMM (proven structure): tile 64(M)x128(N), BK=64, 4 waves,
// wave w owns rows [w*16,w*16+16) x 128 cols (acc[8]). global_load_lds 16B,
// XOR-swizzled LDS. grid = (splitK, N/128, M/64). 24 KB LDS, 4 blocks/CU.
// K-steps q/r-partitioned over gridDim.x. partial[z][m][n].
// ---------------------------------------------------------------------------
__global__ __launch_bounds__(256, 4) void gemm_f16_kernel(
    const unsigned short* __restrict__ A,
    const unsigned short* __restrict__ B,
    float* __restrict__ partial,
    int K2, int N)
{
    __shared__ __align__(16) unsigned short As[64 * 64];    // 8 KB
    __shared__ __align__(16) unsigned short Bs[128 * 64];   // 16 KB

    const int tid  = threadIdx.x;
    const int lane = tid & 63;
    const int wave = tid >> 6;

    const int totalSteps = K2 >> 6;
    const int nz = gridDim.x;
    const int z  = blockIdx.x;
    const int q  = totalSteps / nz, r = totalSteps % nz;
    const int myStart = z * q + min(z, r);
    const int mySteps = q + (z < r ? 1 : 0);

    const int n0 = blockIdx.y * 128;
    const int m0 = blockIdx.z * 64;

    const int rIn  = lane >> 3;
    const int cSrc = (lane & 7) ^ rIn;

    const int mrow = lane & 15, quad = lane >> 4;

    floatx4 acc[8];
#pragma unroll
    for (int j = 0; j < 8; ++j)
        acc[j] = (floatx4){0.f, 0.f, 0.f, 0.f};

    for (int s = 0; s < mySteps; ++s) {
        const int k0 = (myStart + s) * 64;
#pragma unroll
        for (int qq = 0; qq < 2; ++qq) {
            const int rowBase = wave * 16 + qq * 8;
            const unsigned short* ga =
                A + (size_t)(m0 + rowBase + rIn) * K2 + k0 + cSrc * 8;
            __builtin_amdgcn_global_load_lds(
                (const __attribute__((address_space(1))) void*)ga,
                (__attribute__((address_space(3))) void*)&As[rowBase * 64], 16, 0, 0);
        }
#pragma unroll
        for (int qq = 0; qq < 4; ++qq) {
            const int rowBase = wave * 32 + qq * 8;
            const unsigned short* gb =
                B + (size_t)(n0 + rowBase + rIn) * K2 + k0 + cSrc * 8;
            __builtin_amdgcn_global_load_lds(
                (const __attribute__((address_space(1))) void*)gb,
                (__attribute__((address_space(3))) void*)&Bs[rowBase * 64], 16, 0, 0);
        }
        __syncthreads();

#pragma unroll
        for (int ks = 0; ks < 2; ++ks) {
            const int ra = wave * 16 + mrow;
            const int ca = ((ks * 4 + quad) ^ (ra & 7)) * 8;
            const f16x8 aF = *reinterpret_cast<const f16x8*>(&As[ra * 64 + ca]);
#pragma unroll
            for (int j = 0; j < 8; ++j) {
                const int rb = j * 16 + mrow;
                const int cb = ((ks * 4 + quad) ^ (rb & 7)) * 8;
                const f16x8 bF = *reinterpret_cast<const f16x8*>(&Bs[rb * 64 + cb]);
                acc[j] = __builtin_amdgcn_mfma_f32_16x16x32_f16(aF, bF, acc[j], 0, 0, 0);
            }
        }
        __syncthreads();
    }

    float* p = partial + (size_t)blockIdx.x * (size_t)(gridDim.z * 64) * N;
    const int row = m0 + wave * 16 + quad * 4;
#pragma unroll
    for (int j = 0; j < 8; ++j) {
        const int col = n0 + j * 16 + mrow;
#pragma unroll
        for (int rr = 0; rr < 4; ++rr)
            p[(size_t)(row + rr) * N + col] = acc[j][rr];
    }
}

// ---------------------------------------------------------------------------
// fc = relu(sum_z partial + bias) -> fp16. uint2 packed store.
// ---------------------------------------------------------------------------
__global__ __launch_bounds__(256) void reduce_fc_kernel(
    const float* __restrict__ partial, const float* __restrict__ bias,
    _Float16* __restrict__ outH, int nz)
{
    const int i4 = blockIdx.x * 256 + threadIdx.x;
    const int off = i4 * 4;
    const int n = off & 1023;
    float4 acc = *reinterpret_cast<const float4*>(partial + off);
    for (int z = 1; z < nz; ++z) {
        const float4 v = *reinterpret_cast<const float4*>(
            partial + (size_t)z * 1024 * 1024 + off);
        acc.x += v.x; acc.y += v.y; acc.z += v.z; acc.w += v.w;
    }
    const float4 bv = *reinterpret_cast<const float4*>(bias + n);
    union { _Float16 h[4]; uint2 u; } pk;
    pk.h[0] = (_Float16)fmaxf(acc.x + bv.x, 0.f);
    pk.h[1] = (_Float16)fmaxf(acc.y + bv.y, 0.f);
    pk.h[2] = (_Float16)fmaxf(acc.z + bv.z, 0.f);
    pk.h[3] = (_Float16)fmaxf(acc.w + bv.w, 0.f);
    *reinterpret_cast<uint2*>(outH + off) = pk.u;
}

// heads: sum partials [z][1024][512], add bias, split-store to out0/out1
__global__ __launch_bounds__(256) void reduce_heads_kernel(
    const float* __restrict__ partial, const float* __restrict__ bloc,
    const float* __restrict__ bsc, float* __restrict__ out0,
    float* __restrict__ out1, int nz)
{
    const int m = blockIdx.x;   // 0..999
    for (int n = threadIdx.x; n < NH; n += 256) {
        float s = 0.f;
        for (int z = 0; z < nz; ++z)
            s += partial[(size_t)z * 1024 * 512 + (size_t)m * 512 + n];
        if (n < NLOC) out0[(size_t)m * NLOC + n] = s + bloc[n];
        else          out1[(size_t)m * NSC + (n - NLOC)] = s + bsc[n - NLOC];
    }
}

// ---------------------------------------------------------------------------
extern "C" void kernel_launch(void* const* d_in, const int* in_sizes, int n_in,
                              void* d_out, int out_size, void* d_ws, size_t ws_size,
                              hipStream_t stream)
{
    const float* f2   = (const float*)d_in[0];
    const float* f3   = (const float*)d_in[1];
    const float* f4   = (const float*)d_in[2];
    const float* f5   = (const float*)d_in[3];
    const float* rois = (const float*)d_in[4];
    const int*   img  = (const int*)d_in[5];
    const float* W1   = (const float*)d_in[6];
    const float* b1   = (const float*)d_in[7];
    const float* W2   = (const float*)d_in[8];
    const float* b2   = (const float*)d_in[9];
    const float* Wloc = (const float*)d_in[10];
    const float* bloc = (const float*)d_in[11];
    const float* Wsc  = (const float*)d_in[12];
    const float* bsc  = (const float*)d_in[13];
    float* out = (float*)d_out;

    float* ws = (float*)d_ws;
    _Float16*  fT     = (_Float16*)(ws + OFF_FT);
    _Float16*  pooled = (_Float16*)(ws + OFF_POOL);
    _Float16*  w1t    = (_Float16*)(ws + OFF_W1T);
    float*     part1  = ws + OFF_PART1;
    float*     part2  = ws + OFF_PART2;
    _Float16*  fc1    = (_Float16*)(ws + OFF_FC1);
    _Float16*  w2t    = (_Float16*)(ws + OFF_W2T);
    _Float16*  wht    = (_Float16*)(ws + OFF_WHT);
    _Float16*  fc2    = (_Float16*)(ws + OFF_FC2);

    // 1) feature transpose to [pix][256] fp16
    transpose_feat_kernel<<<dim3(5440), 256, 0, stream>>>(f2, f3, f4, f5, fT);

    // 2) fused ROI pool + all weight conversions (overlapped)
    pool_prep_kernel<<<dim3(10520), 256, 0, stream>>>(
        fT, rois, img, pooled, W1, w1t, W2, Wloc, Wsc, w2t, wht);

    // 3) fc1 = relu(pooled @ W1 + b1): K=12544, grid (8,8,16)=1024 blocks
    gemm_f16_kernel<<<dim3(8, 8, 16), 256, 0, stream>>>(
        (const unsigned short*)pooled, (const unsigned short*)w1t, part1,
        PD, 1024);
    reduce_fc_kernel<<<1024, 256, 0, stream>>>(part1, b1, fc1, 8);

    // 4) fc2 = relu(fc1 @ W2 + b2): K=1024, grid (4,8,16)=512 blocks
    gemm_f16_kernel<<<dim3(4, 8, 16), 256, 0, stream>>>(
        (const unsigned short*)fc1, (const unsigned short*)w2t, part2,
        KFC, 1024);
    reduce_fc_kernel<<<1024, 256, 0, stream>>>(part2, b2, fc2, 4);

    // 5) heads: K=1024, N=512, grid (8,4,16)=512 blocks
    gemm_f16_kernel<<<dim3(8, 4, 16), 256, 0, stream>>>(
        (const unsigned short*)fc2, (const unsigned short*)wht, part2,
        KFC, 512);
    reduce_heads_kernel<<<NROIS, 256, 0, stream>>>(
        part2, bloc, bsc, out, out + (size_t)NROIS * NLOC, 8);
}